// Round 7
// baseline (434.722 us; speedup 1.0000x reference)
//
#include <hip/hip_runtime.h>
#include <stdint.h>

// Problem constants (fixed by setup_inputs)
#define B_ 8
#define T_ 4096
#define D_ 1024
#define S_ 64
#define N_ 32768            // B*T
#define OUT_ELEMS 33554432  // N*D
#define NCHK 128            // scan chunks per batch
#define CHKL 32             // T_/NCHK

typedef __attribute__((ext_vector_type(8))) short bf16x8;
typedef __attribute__((ext_vector_type(8))) unsigned short u16x8;
typedef __attribute__((ext_vector_type(4))) float f32x4;

__device__ __forceinline__ uint16_t f2bf(float f) {
    union { float f; uint32_t u; } v; v.f = f;
    uint32_t r = v.u + 0x7FFFu + ((v.u >> 16) & 1u);
    return (uint16_t)(r >> 16);
}
__device__ __forceinline__ float bf2f(uint16_t h) {
    union { uint32_t u; float f; } v; v.u = ((uint32_t)h) << 16;
    return v.f;
}

// async global->LDS, 16B per lane; LDS dest = wave-uniform base + lane*16
#define GLOAD_LDS16(gp, lp)                                             \
    __builtin_amdgcn_global_load_lds(                                   \
        (const __attribute__((address_space(1))) void*)(gp),            \
        (__attribute__((address_space(3))) void*)(lp), 16, 0, 0)

// ---------------- P0: fused prep --------------------------------------------
// blocks [0,2048): grid-stride cast x f32->bf16
// blocks [2048,3298): weight casts (lnw folded into Wkey/Wval) + gate + efirst
// blocks [3298,3554): u/c dot vectors: uk,ck,uv,cv (S=64 each)
__global__ void prep(const float* __restrict__ x,
                     const float* __restrict__ Wsf, const float* __restrict__ Wkf,
                     const float* __restrict__ Wvf, const float* __restrict__ Wof,
                     const float* __restrict__ sg, const float* __restrict__ tf,
                     const float* __restrict__ lnw, const float* __restrict__ lnb,
                     uint16_t* __restrict__ xb, uint16_t* __restrict__ Wsb,
                     uint16_t* __restrict__ Wkvb, uint16_t* __restrict__ Wob,
                     float* __restrict__ gbuf, float* __restrict__ efirst,
                     float* __restrict__ ucvec)
{
    __shared__ float red[4];
    const int blk = blockIdx.x, tid = threadIdx.x;
    if (blk < 2048) {
        for (int i = blk * 256 + tid; i < OUT_ELEMS / 4; i += 2048 * 256) {
            float4 v = ((const float4*)x)[i];
            ushort4 o;
            o.x = f2bf(v.x); o.y = f2bf(v.y); o.z = f2bf(v.z); o.w = f2bf(v.w);
            ((ushort4*)xb)[i] = o;
        }
        return;
    }
    if (blk < 3298) {
        int i = (blk - 2048) * 256 + tid;
        const float* src; uint16_t* dst; int j; bool fold = false;
        if (i < 262144) { src = Wsf; dst = Wsb; j = i; }
        else if (i < 278528) { src = Wkf; dst = Wkvb; j = i - 262144; fold = true; }
        else if (i < 294912) { src = Wvf; dst = Wkvb + 65536; j = i - 278528; fold = true; }
        else if (i < 311296) { src = Wof; dst = Wob; j = i - 294912; }
        else if (i < 311552) {
            j = i - 311296;
            float4 v = ((const float4*)sg)[j];
            float4 g;
            g.x = 1.f / (1.f + __expf(-v.x)); g.y = 1.f / (1.f + __expf(-v.y));
            g.z = 1.f / (1.f + __expf(-v.z)); g.w = 1.f / (1.f + __expf(-v.w));
            ((float4*)gbuf)[j] = g;
            return;
        } else if (i < 311568) {
            j = i - 311552;
            float4 v = ((const float4*)tf)[j];
            float4 e;
            e.x = __expf(v.x); e.y = __expf(v.y); e.z = __expf(v.z); e.w = __expf(v.w);
            ((float4*)efirst)[j] = e;
            return;
        } else return;
        float4 v = ((const float4*)src)[j];
        if (fold) {
            float4 l = ((const float4*)lnw)[j & 255];   // col4 within row of 1024
            v.x *= l.x; v.y *= l.y; v.z *= l.z; v.w *= l.w;
        }
        ushort4 o;
        o.x = f2bf(v.x); o.y = f2bf(v.y); o.z = f2bf(v.z); o.w = f2bf(v.w);
        ((ushort4*)dst)[j] = o;
        return;
    }
    {
        int b2 = blk - 3298;
        int which = b2 >> 6, s = b2 & 63;      // 0:uk 1:ck 2:uv 3:cv
        const float* W = (which < 2) ? Wkf : Wvf;
        const float* L = (which & 1) ? lnb : lnw;
        float4 wv = ((const float4*)W)[s * 256 + tid];
        float4 lv = ((const float4*)L)[tid];
        float p = wv.x * lv.x + wv.y * lv.y + wv.z * lv.z + wv.w * lv.w;
#pragma unroll
        for (int off = 32; off; off >>= 1) p += __shfl_xor(p, off);
        if ((tid & 63) == 0) red[tid >> 6] = p;
        __syncthreads();
        if (tid == 0) ucvec[which * 64 + s] = red[0] + red[1] + red[2] + red[3];
    }
}

// ---------------- K1: x_shift = (x_cat @ Wshift^T)*g + x*(1-g) -> bf16 ------
// 256x256 tile, BK=64, 512 threads = 8 waves (2M x 4N), wave tile 128x64.
// 2 slots x 64KB LDS, distance-1 prefetch, one vmcnt drain per 64 MFMAs.
// (Reverted to the proven R5 body: 95 us; 8-phase variant measured slower.)
__global__ __launch_bounds__(512, 2) void k1_shift_gemm(
    const uint16_t* __restrict__ xb, const uint16_t* __restrict__ Wsb,
    const float* __restrict__ gbuf, uint16_t* __restrict__ xs)
{
    __shared__ char sh[131072];                 // 2 slots x (A 32KB + B 32KB)

    const int tid = threadIdx.x;
    const int w = tid >> 6, lane = tid & 63, quad = lane >> 4, l16 = lane & 15;
    const int wm = w >> 2, wn = w & 3;          // 2M x 4N waves
    const int w8 = w * 8;                       // staging row base per wave

    const int lin = blockIdx.x;                 // 512 blocks
    const int idx = lin >> 3;                   // [0,64)
    const int nt = idx & 3;
    const int mt = (lin & 7) * 16 + (idx >> 2); // XCD-local m-ranges
    const int m0 = mt * 256, n0 = nt * 256;
    const int m0x = m0 ^ 2048;                  // x_cat[t] = x[t ^ T/2]; no straddle

    // staging lane addressing (pre-swizzled global source, linear LDS dest)
    const int arow = w8 + (lane >> 3);
    const int scg  = ((lane & 7) ^ ((lane >> 3) & 7)) * 8;
    const uint16_t* aBase = xb  + (size_t)(m0x + arow) * D_ + scg;
    const uint16_t* bBase = Wsb + (size_t)(n0  + arow) * D_ + scg;

    // ds_read swizzled column offsets (elements)
    const int swz0 = ((quad) ^ (l16 & 7)) * 8;        // ks=0
    const int swz1 = ((4 + quad) ^ (l16 & 7)) * 8;    // ks=1
    const int aRowBase = wm * 128 + l16;
    const int bRowBase = wn * 64 + l16;

    f32x4 acc[8][4];
#pragma unroll
    for (int i = 0; i < 8; ++i)
#pragma unroll
        for (int j = 0; j < 4; ++j) acc[i][j] = (f32x4){0.f, 0.f, 0.f, 0.f};

    // ---- prologue: stage K-tile 0 into slot 0 ------------------------------
    {
        uint16_t (*A0)[64] = (uint16_t(*)[64])(sh);
        uint16_t (*B0)[64] = (uint16_t(*)[64])(sh + 32768);
#pragma unroll
        for (int c = 0; c < 4; ++c) {
            GLOAD_LDS16(aBase + (size_t)(c * 64) * D_, &A0[c * 64 + w8][0]);
            GLOAD_LDS16(bBase + (size_t)(c * 64) * D_, &B0[c * 64 + w8][0]);
        }
    }
    asm volatile("s_waitcnt vmcnt(0)" ::: "memory");
    __builtin_amdgcn_s_barrier();

    // ---- main loop: 16 K-tiles, 2 phases each ------------------------------
#pragma unroll 1
    for (int t = 0; t < 16; ++t) {
        const int c = t & 1, o = c ^ 1;
        uint16_t (*Ac)[64] = (uint16_t(*)[64])(sh + c * 65536);
        uint16_t (*Bc)[64] = (uint16_t(*)[64])(sh + c * 65536 + 32768);
        uint16_t (*Ao)[64] = (uint16_t(*)[64])(sh + o * 65536);
        uint16_t (*Bo)[64] = (uint16_t(*)[64])(sh + o * 65536 + 32768);
        const int kb1 = (t + 1) * 64;

#pragma unroll
        for (int ks = 0; ks < 2; ++ks) {
            const int swz = ks ? swz1 : swz0;
            bf16x8 a[8], b[4];
#pragma unroll
            for (int mf = 0; mf < 8; ++mf)
                a[mf] = *(const bf16x8*)&Ac[aRowBase + mf * 16][swz];
#pragma unroll
            for (int nf = 0; nf < 4; ++nf)
                b[nf] = *(const bf16x8*)&Bc[bRowBase + nf * 16][swz];
            if (ks == 0 && t < 15) {
#pragma unroll
                for (int cc = 0; cc < 4; ++cc) {
                    GLOAD_LDS16(aBase + (size_t)(cc * 64) * D_ + kb1,
                                &Ao[cc * 64 + w8][0]);
                    GLOAD_LDS16(bBase + (size_t)(cc * 64) * D_ + kb1,
                                &Bo[cc * 64 + w8][0]);
                }
            }
            if (ks == 1 && t < 15) {
                asm volatile("s_waitcnt vmcnt(0)" ::: "memory");
            }
            __builtin_amdgcn_s_barrier();
            __builtin_amdgcn_s_setprio(1);
#pragma unroll
            for (int mf = 0; mf < 8; ++mf)
#pragma unroll
                for (int nf = 0; nf < 4; ++nf)
                    acc[mf][nf] = __builtin_amdgcn_mfma_f32_16x16x32_bf16(
                        a[mf], b[nf], acc[mf][nf], 0, 0, 0);
            __builtin_amdgcn_s_setprio(0);
        }
    }

    // ---- epilogue: 4 passes of 64 rows through LDS, blend + bf16 store -----
    float (*epi)[260] = (float(*)[260])sh;       // 64 x 260 f32 = 65 KB
    const int row = tid >> 3;
    const int c0 = (tid & 7) * 32;
#pragma unroll
    for (int mb = 0; mb < 4; ++mb) {
        __syncthreads();
        if (wm == (mb >> 1)) {
#pragma unroll
            for (int mf = 0; mf < 4; ++mf)
#pragma unroll
                for (int nf = 0; nf < 4; ++nf)
#pragma unroll
                    for (int r = 0; r < 4; ++r)
                        epi[mf * 16 + quad * 4 + r][wn * 64 + nf * 16 + l16] =
                            acc[(mb & 1) * 4 + mf][nf][r];
        }
        __syncthreads();
        const int grow = m0 + mb * 64 + row;
        const uint16_t* xrow = xb + (size_t)grow * D_ + n0 + c0;
        uint16_t* orow = xs + (size_t)grow * D_ + n0 + c0;
#pragma unroll
        for (int c4 = 0; c4 < 8; ++c4) {
            float4 g4 = ((const float4*)(gbuf + n0 + c0))[c4];
            ushort4 xh = ((const ushort4*)xrow)[c4];
            const float* e = &epi[row][c0 + c4 * 4];
            ushort4 o;
            o.x = f2bf(e[0] * g4.x + bf2f(xh.x) * (1.f - g4.x));
            o.y = f2bf(e[1] * g4.y + bf2f(xh.y) * (1.f - g4.y));
            o.z = f2bf(e[2] * g4.z + bf2f(xh.z) * (1.f - g4.z));
            o.w = f2bf(e[3] * g4.w + bf2f(xh.w) * (1.f - g4.w));
            ((ushort4*)orow)[c4] = o;
        }
    }
}

// ---------------- K3: k/v projection + MFMA row stats + analytic LN + wkv
//                       + fused k4a (per-chunk weighted sums -> part) --------
__global__ __launch_bounds__(256) void k3_kv(
    const uint16_t* __restrict__ xsb, const uint16_t* __restrict__ Wkvb,
    const float* __restrict__ efirst, const float* __restrict__ ucvec,
    const float* __restrict__ time_decay,
    float* __restrict__ wkv, float* __restrict__ part)
{
    __shared__ char sh[52224];
    uint16_t (*As)[64] = (uint16_t(*)[64])sh;           // [64][64]  8 KB
    uint16_t (*Bs)[64] = (uint16_t(*)[64])(sh + 8192);  // [128][64] 16 KB
    float (*epi)[132] = (float(*)[132])sh;              // [64][132] f32 (union)
    float* ssh = (float*)(sh + 33792);                  // [64] row sums
    float* qsh = (float*)(sh + 34048);                  // [64] row sumsq
    float (*wsh)[68] = (float(*)[68])(sh + 34816);      // [64][68] wkv stash 17KB

    const int tid = threadIdx.x;
    const int w = tid >> 6, lane = tid & 63, quad = lane >> 4, l16 = lane & 15;
    const int wm = w >> 1, wn = w & 1;
    const int m0 = blockIdx.x * 64;

    const int lrow = w * 8 + (lane >> 3);
    const int scg  = ((lane & 7) ^ ((lane >> 3) & 7)) * 8;
    const uint16_t* aG = xsb + (size_t)(m0 + lrow) * D_ + scg;
    const uint16_t* bG = Wkvb + (size_t)lrow * D_ + scg;

    f32x4 acc[2][4];
#pragma unroll
    for (int i = 0; i < 2; ++i)
#pragma unroll
        for (int j = 0; j < 4; ++j) acc[i][j] = (f32x4){0.f, 0.f, 0.f, 0.f};
    f32x4 accs[2], accq[2];
#pragma unroll
    for (int i = 0; i < 2; ++i) {
        accs[i] = (f32x4){0.f, 0.f, 0.f, 0.f};
        accq[i] = (f32x4){0.f, 0.f, 0.f, 0.f};
    }
    bf16x8 ones;
#pragma unroll
    for (int j = 0; j < 8; ++j) ones[j] = (short)0x3F80;  // bf16 1.0

    for (int k0 = 0; k0 < D_; k0 += 64) {
        __syncthreads();
#pragma unroll
        for (int i = 0; i < 2; ++i)
            GLOAD_LDS16(aG + k0 + (size_t)(i * 32) * D_, &As[w * 8 + i * 32][0]);
#pragma unroll
        for (int i = 0; i < 4; ++i)
            GLOAD_LDS16(bG + k0 + (size_t)(i * 32) * D_, &Bs[w * 8 + i * 32][0]);
        __syncthreads();
#pragma unroll
        for (int ks = 0; ks < 2; ++ks) {
            bf16x8 a[2], b[4];
#pragma unroll
            for (int i = 0; i < 2; ++i)
                a[i] = *(const bf16x8*)&As[wm * 32 + i * 16 + l16]
                                         [(((ks * 4 + quad) ^ (l16 & 7)) * 8)];
#pragma unroll
            for (int j = 0; j < 4; ++j)
                b[j] = *(const bf16x8*)&Bs[wn * 64 + j * 16 + l16]
                                         [(((ks * 4 + quad) ^ (l16 & 7)) * 8)];
#pragma unroll
            for (int i = 0; i < 2; ++i)
#pragma unroll
                for (int j = 0; j < 4; ++j)
                    acc[i][j] = __builtin_amdgcn_mfma_f32_16x16x32_bf16(
                        a[i], b[j], acc[i][j], 0, 0, 0);
            if (wn == 0) {   // wave-uniform: stats on the 2 wn==0 waves only
#pragma unroll
                for (int i = 0; i < 2; ++i) {
                    accs[i] = __builtin_amdgcn_mfma_f32_16x16x32_bf16(
                        a[i], ones, accs[i], 0, 0, 0);
                    accq[i] = __builtin_amdgcn_mfma_f32_16x16x32_bf16(
                        a[i], a[i], accq[i], 0, 0, 0);
                }
            }
        }
    }

    // extract row stats: C layout col=lane&15, row=quad*4+reg
    if (wn == 0) {
#pragma unroll
        for (int i = 0; i < 2; ++i) {
            if (l16 == 0) {
#pragma unroll
                for (int r = 0; r < 4; ++r)
                    ssh[wm * 32 + i * 16 + quad * 4 + r] = accs[i][r];
            }
            if ((l16 >> 2) == quad)
                qsh[wm * 32 + i * 16 + l16] = accq[i][l16 & 3];
        }
    }

    __syncthreads();
#pragma unroll
    for (int i = 0; i < 2; ++i)
#pragma unroll
        for (int j = 0; j < 4; ++j)
#pragma unroll
            for (int r = 0; r < 4; ++r)
                epi[wm * 32 + i * 16 + quad * 4 + r][wn * 64 + j * 16 + l16] =
                    acc[i][j][r];
    __syncthreads();

    // epilogue: analytic LN affine then wkv = exp(-exp(tf)*sigmoid(k)) * v
    const int row = tid >> 2, s0 = (tid & 3) * 16;
    const float mu = ssh[row] * (1.f / (float)D_);
    const float var = qsh[row] * (1.f / (float)D_) - mu * mu;
    const float rstd = rsqrtf(var + 1e-5f);
    float* dst = wkv + (size_t)(m0 + row) * S_ + s0;
#pragma unroll
    for (int c4 = 0; c4 < 4; ++c4) {
        float4 kk = *(const float4*)&epi[row][s0 + c4 * 4];
        float4 vv = *(const float4*)&epi[row][64 + s0 + c4 * 4];
        float4 uk4 = *(const float4*)(ucvec + 0 * 64 + s0 + c4 * 4);
        float4 ck4 = *(const float4*)(ucvec + 1 * 64 + s0 + c4 * 4);
        float4 uv4 = *(const float4*)(ucvec + 2 * 64 + s0 + c4 * 4);
        float4 cv4 = *(const float4*)(ucvec + 3 * 64 + s0 + c4 * 4);
        float4 ef = ((const float4*)(efirst + s0))[c4];
        float kx = rstd * (kk.x - mu * uk4.x) + ck4.x;
        float ky = rstd * (kk.y - mu * uk4.y) + ck4.y;
        float kz = rstd * (kk.z - mu * uk4.z) + ck4.z;
        float kw = rstd * (kk.w - mu * uk4.w) + ck4.w;
        float vx = rstd * (vv.x - mu * uv4.x) + cv4.x;
        float vy = rstd * (vv.y - mu * uv4.y) + cv4.y;
        float vz = rstd * (vv.z - mu * uv4.z) + cv4.z;
        float vw = rstd * (vv.w - mu * uv4.w) + cv4.w;
        float4 o;
        o.x = __expf(-ef.x / (1.f + __expf(-kx))) * vx;
        o.y = __expf(-ef.y / (1.f + __expf(-ky))) * vy;
        o.z = __expf(-ef.z / (1.f + __expf(-kz))) * vz;
        o.w = __expf(-ef.w / (1.f + __expf(-kw))) * vw;
        *(float4*)(dst + c4 * 4) = o;
        *(float4*)&wsh[row][s0 + c4 * 4] = o;     // stash for part-sum
    }

    // fused k4a: per-chunk weighted sums. Block covers 2 chunks of 32 rows.
    __syncthreads();
    if (tid < 128) {
        const int ch = tid >> 6, s = tid & 63;
        const float w1 = expf(time_decay[s]);
        float st = 0.f;
#pragma unroll
        for (int t = 0; t < CHKL; ++t)
            st = st * w1 + wsh[ch * CHKL + t][s];
        const int b = m0 >> 12;                       // m0 / 4096
        const int gc = ((m0 & 4095) >> 5) + ch;       // global chunk in batch
        part[((size_t)b * NCHK + gc) * S_ + s] = st;
    }
}

// ---------------- K5: scan (fused k4bc) + output GEMM -----------------------
// Each block: 128 rows = 4 chunks of one batch. Wave w scans chunk c0+w
// (lane = s): carry prefix from part, then 32 steps; states -> swizzled LDS
// bf16 tile; then GEMM states(128x64) x Wout^T(128 cols) -> out.
__global__ __launch_bounds__(256) void k5_out(
    const float* __restrict__ wkv, const float* __restrict__ part,
    const float* __restrict__ time_decay, const uint16_t* __restrict__ Wob,
    float* __restrict__ out, float* __restrict__ last_state)
{
    __shared__ char sh[34816];
    uint16_t (*stS)[64] = (uint16_t(*)[64])sh;   // [128][64] bf16, 16 KB
    float (*epi)[68] = (float(*)[68])sh;         // [128][68] f32 (union, later)

    const int tid = threadIdx.x;
    const int w = tid >> 6, lane = tid & 63, quad = lane >> 4, l16 = lane & 15;
    const int wm = w >> 1, wn = w & 1;
    const int m0b = blockIdx.y * 128;
    const int n0b = blockIdx.x * 128;

    // ---- scan phase: wave w owns chunk c = c0 + w --------------------------
    {
        const int b = m0b >> 12;
        const int c = ((m0b & 4095) >> 5) + w;
        const float td = time_decay[lane];
        const float w1 = expf(td);
        const float wL = expf(td * (float)CHKL);
        const float* pp = part + (size_t)b * NCHK * S_ + lane;
        float cin = 0.f;
        for (int j = 0; j < c; ++j) cin = cin * wL + pp[(size_t)j * S_];
        const float* src = wkv + (size_t)(m0b + w * CHKL) * S_ + lane;
        float st = cin;
#pragma unroll
        for (int t = 0; t < CHKL; ++t) {
            st = st * w1 + src[(size_t)t * S_];
            const int row = w * CHKL + t;
            stS[row][(((lane >> 3) ^ (row & 7)) << 3) | (lane & 7)] = f2bf(st);
        }
        if (n0b == 0 && c == NCHK - 1)
            last_state[b * S_ + lane] = st;
    }
    __syncthreads();

    f32x4 acc[4][4];
#pragma unroll
    for (int i = 0; i < 4; ++i)
#pragma unroll
        for (int j = 0; j < 4; ++j) acc[i][j] = (f32x4){0.f, 0.f, 0.f, 0.f};

#pragma unroll
    for (int k = 0; k < S_; k += 32) {
        bf16x8 a[4], b[4];
#pragma unroll
        for (int i = 0; i < 4; ++i) {
            const int row = wm * 64 + i * 16 + l16;
            a[i] = *(const bf16x8*)&stS[row]
                       [((((k >> 3) + quad) ^ (l16 & 7)) * 8)];
        }
#pragma unroll
        for (int i = 0; i < 4; ++i)
            b[i] = *(const bf16x8*)(Wob + (size_t)(n0b + wn * 64 + i * 16 + l16) * S_ + k + quad * 8);
#pragma unroll
        for (int i = 0; i < 4; ++i)
#pragma unroll
            for (int j = 0; j < 4; ++j)
                acc[i][j] = __builtin_amdgcn_mfma_f32_16x16x32_bf16(
                    a[i], b[j], acc[i][j], 0, 0, 0);
    }

    const int row = tid >> 1;
    const int c0 = (tid & 1) * 32;
#pragma unroll
    for (int h = 0; h < 2; ++h) {
        __syncthreads();
        if (wn == h) {
#pragma unroll
            for (int i = 0; i < 4; ++i)
#pragma unroll
                for (int j = 0; j < 4; ++j)
#pragma unroll
                    for (int r = 0; r < 4; ++r)
                        epi[wm * 64 + i * 16 + quad * 4 + r][j * 16 + l16] =
                            acc[i][j][r];
        }
        __syncthreads();
        float* dst = out + (size_t)(m0b + row) * D_ + n0b + h * 64 + c0;
#pragma unroll
        for (int c4 = 0; c4 < 8; ++c4)
            ((float4*)dst)[c4] = *(const float4*)&epi[row][c0 + c4 * 4];
    }
}

extern "C" void kernel_launch(void* const* d_in, const int* in_sizes, int n_in,
                              void* d_out, int out_size, void* d_ws, size_t ws_size,
                              hipStream_t stream) {
    const float* x          = (const float*)d_in[0];
    const float* time_decay = (const float*)d_in[1];
    const float* time_first = (const float*)d_in[2];
    const float* W_key      = (const float*)d_in[3];
    const float* W_value    = (const float*)d_in[4];
    const float* W_output   = (const float*)d_in[5];
    const float* W_shift    = (const float*)d_in[6];
    const float* shift_gate = (const float*)d_in[7];
    const float* ln_w       = (const float*)d_in[8];
    const float* ln_b       = (const float*)d_in[9];
    float* out = (float*)d_out;

    char* ws = (char*)d_ws;
    uint16_t* xb      = (uint16_t*)(ws + 0);           // N*D bf16   = 64 MB
    uint16_t* xs      = (uint16_t*)(ws + 67108864);    // N*D bf16   = 64 MB
    float*    wkv     = (float*)   (ws + 134217728);   // N*S f32    =  8 MB
    uint16_t* Wsb     = (uint16_t*)(ws + 146800640);   // D*D bf16   =  2 MB
    uint16_t* Wkvb    = (uint16_t*)(ws + 148897792);   // 128*D bf16 = 256 KB
    uint16_t* Wob     = (uint16_t*)(ws + 149159936);   // D*S bf16   = 128 KB
    float*    part    = (float*)   (ws + 149291008);   // B*NCHK*S   = 256 KB
    float*    gbuf    = (float*)   (ws + 149815296);   // D f32      =   4 KB
    float*    efirst  = (float*)   (ws + 149819392);   // S f32      = 256 B
    float*    ucvec   = (float*)   (ws + 149819648);   // 4*S f32    =   1 KB

    prep<<<3554, 256, 0, stream>>>(x, W_shift, W_key, W_value, W_output,
                                   shift_gate, time_first, ln_w, ln_b,
                                   xb, Wsb, Wkvb, Wob, gbuf, efirst, ucvec);
    k1_shift_gemm<<<512, 512, 0, stream>>>(xb, Wsb, gbuf, xs);
    k3_kv<<<512, 256, 0, stream>>>(xs, Wkvb, efirst, ucvec, time_decay,
                                   wkv, part);
    k5_out<<<dim3(8, 256), 256, 0, stream>>>(wkv, part, time_decay, Wob,
                                             out, out + OUT_ELEMS);
}

// Round 8
// 427.065 us; speedup vs baseline: 1.0179x; 1.0179x over previous
//
#include <hip/hip_runtime.h>
#include <stdint.h>

// Problem constants (fixed by setup_inputs)
#define B_ 8
#define T_ 4096
#define D_ 1024
#define S_ 64
#define N_ 32768            // B*T
#define OUT_ELEMS 33554432  // N*D
#define NCHK 128            // scan chunks per batch
#define CHKL 32             // T_/NCHK

typedef __attribute__((ext_vector_type(8))) short bf16x8;
typedef __attribute__((ext_vector_type(8))) unsigned short u16x8;
typedef __attribute__((ext_vector_type(4))) float f32x4;

__device__ __forceinline__ uint16_t f2bf(float f) {
    union { float f; uint32_t u; } v; v.f = f;
    uint32_t r = v.u + 0x7FFFu + ((v.u >> 16) & 1u);
    return (uint16_t)(r >> 16);
}
__device__ __forceinline__ float bf2f(uint16_t h) {
    union { uint32_t u; float f; } v; v.u = ((uint32_t)h) << 16;
    return v.f;
}

// async global->LDS, 16B per lane; LDS dest = wave-uniform base + lane*16
#define GLOAD_LDS16(gp, lp)                                             \
    __builtin_amdgcn_global_load_lds(                                   \
        (const __attribute__((address_space(1))) void*)(gp),            \
        (__attribute__((address_space(3))) void*)(lp), 16, 0, 0)

// ---------------- P0: fused prep --------------------------------------------
__global__ void prep(const float* __restrict__ x,
                     const float* __restrict__ Wsf, const float* __restrict__ Wkf,
                     const float* __restrict__ Wvf, const float* __restrict__ Wof,
                     const float* __restrict__ sg, const float* __restrict__ tf,
                     const float* __restrict__ lnw, const float* __restrict__ lnb,
                     uint16_t* __restrict__ xb, uint16_t* __restrict__ Wsb,
                     uint16_t* __restrict__ Wkvb, uint16_t* __restrict__ Wob,
                     float* __restrict__ gbuf, float* __restrict__ efirst,
                     float* __restrict__ ucvec)
{
    __shared__ float red[4];
    const int blk = blockIdx.x, tid = threadIdx.x;
    if (blk < 2048) {
        for (int i = blk * 256 + tid; i < OUT_ELEMS / 4; i += 2048 * 256) {
            float4 v = ((const float4*)x)[i];
            ushort4 o;
            o.x = f2bf(v.x); o.y = f2bf(v.y); o.z = f2bf(v.z); o.w = f2bf(v.w);
            ((ushort4*)xb)[i] = o;
        }
        return;
    }
    if (blk < 3298) {
        int i = (blk - 2048) * 256 + tid;
        const float* src; uint16_t* dst; int j; bool fold = false;
        if (i < 262144) { src = Wsf; dst = Wsb; j = i; }
        else if (i < 278528) { src = Wkf; dst = Wkvb; j = i - 262144; fold = true; }
        else if (i < 294912) { src = Wvf; dst = Wkvb + 65536; j = i - 278528; fold = true; }
        else if (i < 311296) { src = Wof; dst = Wob; j = i - 294912; }
        else if (i < 311552) {
            j = i - 311296;
            float4 v = ((const float4*)sg)[j];
            float4 g;
            g.x = 1.f / (1.f + __expf(-v.x)); g.y = 1.f / (1.f + __expf(-v.y));
            g.z = 1.f / (1.f + __expf(-v.z)); g.w = 1.f / (1.f + __expf(-v.w));
            ((float4*)gbuf)[j] = g;
            return;
        } else if (i < 311568) {
            j = i - 311552;
            float4 v = ((const float4*)tf)[j];
            float4 e;
            e.x = __expf(v.x); e.y = __expf(v.y); e.z = __expf(v.z); e.w = __expf(v.w);
            ((float4*)efirst)[j] = e;
            return;
        } else return;
        float4 v = ((const float4*)src)[j];
        if (fold) {
            float4 l = ((const float4*)lnw)[j & 255];   // col4 within row of 1024
            v.x *= l.x; v.y *= l.y; v.z *= l.z; v.w *= l.w;
        }
        ushort4 o;
        o.x = f2bf(v.x); o.y = f2bf(v.y); o.z = f2bf(v.z); o.w = f2bf(v.w);
        ((ushort4*)dst)[j] = o;
        return;
    }
    {
        int b2 = blk - 3298;
        int which = b2 >> 6, s = b2 & 63;      // 0:uk 1:ck 2:uv 3:cv
        const float* W = (which < 2) ? Wkf : Wvf;
        const float* L = (which & 1) ? lnb : lnw;
        float4 wv = ((const float4*)W)[s * 256 + tid];
        float4 lv = ((const float4*)L)[tid];
        float p = wv.x * lv.x + wv.y * lv.y + wv.z * lv.z + wv.w * lv.w;
#pragma unroll
        for (int off = 32; off; off >>= 1) p += __shfl_xor(p, off);
        if ((tid & 63) == 0) red[tid >> 6] = p;
        __syncthreads();
        if (tid == 0) ucvec[which * 64 + s] = red[0] + red[1] + red[2] + red[3];
    }
}

// ---------------- K1: x_shift = (x_cat @ Wshift^T)*g + x*(1-g) -> bf16 ------
// 256x256 tile, BK=64, 512 threads = 8 waves (2M x 4N), wave tile 128x64.
// 2 slots x 64KB LDS, distance-1 prefetch, one vmcnt drain per 64 MFMAs.
__global__ __launch_bounds__(512, 2) void k1_shift_gemm(
    const uint16_t* __restrict__ xb, const uint16_t* __restrict__ Wsb,
    const float* __restrict__ gbuf, uint16_t* __restrict__ xs)
{
    __shared__ char sh[131072];                 // 2 slots x (A 32KB + B 32KB)

    const int tid = threadIdx.x;
    const int w = tid >> 6, lane = tid & 63, quad = lane >> 4, l16 = lane & 15;
    const int wm = w >> 2, wn = w & 3;          // 2M x 4N waves
    const int w8 = w * 8;                       // staging row base per wave

    const int lin = blockIdx.x;                 // 512 blocks
    const int idx = lin >> 3;                   // [0,64)
    const int nt = idx & 3;
    const int mt = (lin & 7) * 16 + (idx >> 2); // XCD-local m-ranges
    const int m0 = mt * 256, n0 = nt * 256;
    const int m0x = m0 ^ 2048;                  // x_cat[t] = x[t ^ T/2]; no straddle

    const int arow = w8 + (lane >> 3);
    const int scg  = ((lane & 7) ^ ((lane >> 3) & 7)) * 8;
    const uint16_t* aBase = xb  + (size_t)(m0x + arow) * D_ + scg;
    const uint16_t* bBase = Wsb + (size_t)(n0  + arow) * D_ + scg;

    const int swz0 = ((quad) ^ (l16 & 7)) * 8;        // ks=0
    const int swz1 = ((4 + quad) ^ (l16 & 7)) * 8;    // ks=1
    const int aRowBase = wm * 128 + l16;
    const int bRowBase = wn * 64 + l16;

    f32x4 acc[8][4];
#pragma unroll
    for (int i = 0; i < 8; ++i)
#pragma unroll
        for (int j = 0; j < 4; ++j) acc[i][j] = (f32x4){0.f, 0.f, 0.f, 0.f};

    {
        uint16_t (*A0)[64] = (uint16_t(*)[64])(sh);
        uint16_t (*B0)[64] = (uint16_t(*)[64])(sh + 32768);
#pragma unroll
        for (int c = 0; c < 4; ++c) {
            GLOAD_LDS16(aBase + (size_t)(c * 64) * D_, &A0[c * 64 + w8][0]);
            GLOAD_LDS16(bBase + (size_t)(c * 64) * D_, &B0[c * 64 + w8][0]);
        }
    }
    asm volatile("s_waitcnt vmcnt(0)" ::: "memory");
    __builtin_amdgcn_s_barrier();

#pragma unroll 1
    for (int t = 0; t < 16; ++t) {
        const int c = t & 1, o = c ^ 1;
        uint16_t (*Ac)[64] = (uint16_t(*)[64])(sh + c * 65536);
        uint16_t (*Bc)[64] = (uint16_t(*)[64])(sh + c * 65536 + 32768);
        uint16_t (*Ao)[64] = (uint16_t(*)[64])(sh + o * 65536);
        uint16_t (*Bo)[64] = (uint16_t(*)[64])(sh + o * 65536 + 32768);
        const int kb1 = (t + 1) * 64;

#pragma unroll
        for (int ks = 0; ks < 2; ++ks) {
            const int swz = ks ? swz1 : swz0;
            bf16x8 a[8], b[4];
#pragma unroll
            for (int mf = 0; mf < 8; ++mf)
                a[mf] = *(const bf16x8*)&Ac[aRowBase + mf * 16][swz];
#pragma unroll
            for (int nf = 0; nf < 4; ++nf)
                b[nf] = *(const bf16x8*)&Bc[bRowBase + nf * 16][swz];
            if (ks == 0 && t < 15) {
#pragma unroll
                for (int cc = 0; cc < 4; ++cc) {
                    GLOAD_LDS16(aBase + (size_t)(cc * 64) * D_ + kb1,
                                &Ao[cc * 64 + w8][0]);
                    GLOAD_LDS16(bBase + (size_t)(cc * 64) * D_ + kb1,
                                &Bo[cc * 64 + w8][0]);
                }
            }
            if (ks == 1 && t < 15) {
                asm volatile("s_waitcnt vmcnt(0)" ::: "memory");
            }
            __builtin_amdgcn_s_barrier();
            __builtin_amdgcn_s_setprio(1);
#pragma unroll
            for (int mf = 0; mf < 8; ++mf)
#pragma unroll
                for (int nf = 0; nf < 4; ++nf)
                    acc[mf][nf] = __builtin_amdgcn_mfma_f32_16x16x32_bf16(
                        a[mf], b[nf], acc[mf][nf], 0, 0, 0);
            __builtin_amdgcn_s_setprio(0);
        }
    }

    float (*epi)[260] = (float(*)[260])sh;       // 64 x 260 f32 = 65 KB
    const int row = tid >> 3;
    const int c0 = (tid & 7) * 32;
#pragma unroll
    for (int mb = 0; mb < 4; ++mb) {
        __syncthreads();
        if (wm == (mb >> 1)) {
#pragma unroll
            for (int mf = 0; mf < 4; ++mf)
#pragma unroll
                for (int nf = 0; nf < 4; ++nf)
#pragma unroll
                    for (int r = 0; r < 4; ++r)
                        epi[mf * 16 + quad * 4 + r][wn * 64 + nf * 16 + l16] =
                            acc[(mb & 1) * 4 + mf][nf][r];
        }
        __syncthreads();
        const int grow = m0 + mb * 64 + row;
        const uint16_t* xrow = xb + (size_t)grow * D_ + n0 + c0;
        uint16_t* orow = xs + (size_t)grow * D_ + n0 + c0;
#pragma unroll
        for (int c4 = 0; c4 < 8; ++c4) {
            float4 g4 = ((const float4*)(gbuf + n0 + c0))[c4];
            ushort4 xh = ((const ushort4*)xrow)[c4];
            const float* e = &epi[row][c0 + c4 * 4];
            ushort4 o;
            o.x = f2bf(e[0] * g4.x + bf2f(xh.x) * (1.f - g4.x));
            o.y = f2bf(e[1] * g4.y + bf2f(xh.y) * (1.f - g4.y));
            o.z = f2bf(e[2] * g4.z + bf2f(xh.z) * (1.f - g4.z));
            o.w = f2bf(e[3] * g4.w + bf2f(xh.w) * (1.f - g4.w));
            ((ushort4*)orow)[c4] = o;
        }
    }
}

// ---------------- K3: k/v projection, 128x128 tile, 2-slot pipeline ---------
// + MFMA row stats + analytic LN + wkv + fused k4a (part sums from epi tile).
// 256 threads = 4 waves (2M x 2N), wave tile 64x64.
__global__ __launch_bounds__(256) void k3_kv(
    const uint16_t* __restrict__ xsb, const uint16_t* __restrict__ Wkvb,
    const float* __restrict__ efirst, const float* __restrict__ ucvec,
    const float* __restrict__ time_decay,
    float* __restrict__ wkv, float* __restrict__ part)
{
    __shared__ char sh[68608];
    // pipeline: 2 slots x (A[128][64] 16KB + B[128][64] 16KB) = 64KB
    float (*epi)[132] = (float(*)[132])sh;       // [128][132] f32 = 67.6KB (union)
    float* ssh = (float*)(sh + 67584);           // [128] row sums
    // qsh at 68096

    const int tid = threadIdx.x;
    const int w = tid >> 6, lane = tid & 63, quad = lane >> 4, l16 = lane & 15;
    const int wm = w >> 1, wn = w & 1;
    const int w8 = w * 8;
    const int m0 = blockIdx.x * 128;

    const int arow = w8 + (lane >> 3);
    const int scg  = ((lane & 7) ^ ((lane >> 3) & 7)) * 8;
    const uint16_t* aBase = xsb + (size_t)(m0 + arow) * D_ + scg;
    const uint16_t* bBase = Wkvb + (size_t)arow * D_ + scg;

    const int swz0 = ((quad) ^ (l16 & 7)) * 8;
    const int swz1 = ((4 + quad) ^ (l16 & 7)) * 8;
    const int aRowBase = wm * 64 + l16;
    const int bRowBase = wn * 64 + l16;

    f32x4 acc[4][4];
#pragma unroll
    for (int i = 0; i < 4; ++i)
#pragma unroll
        for (int j = 0; j < 4; ++j) acc[i][j] = (f32x4){0.f, 0.f, 0.f, 0.f};
    f32x4 accs[4], accq[4];
#pragma unroll
    for (int i = 0; i < 4; ++i) {
        accs[i] = (f32x4){0.f, 0.f, 0.f, 0.f};
        accq[i] = (f32x4){0.f, 0.f, 0.f, 0.f};
    }
    bf16x8 ones;
#pragma unroll
    for (int j = 0; j < 8; ++j) ones[j] = (short)0x3F80;  // bf16 1.0

    // prologue: stage K-tile 0 into slot 0 (4 A-calls + 4 B-calls per wave)
    {
        uint16_t (*A0)[64] = (uint16_t(*)[64])(sh);
        uint16_t (*B0)[64] = (uint16_t(*)[64])(sh + 16384);
#pragma unroll
        for (int c = 0; c < 4; ++c) {
            GLOAD_LDS16(aBase + (size_t)(c * 32) * D_, &A0[c * 32 + w8][0]);
            GLOAD_LDS16(bBase + (size_t)(c * 32) * D_, &B0[c * 32 + w8][0]);
        }
    }
    asm volatile("s_waitcnt vmcnt(0)" ::: "memory");
    __builtin_amdgcn_s_barrier();

#pragma unroll 1
    for (int t = 0; t < 16; ++t) {
        const int c = t & 1, o = c ^ 1;
        uint16_t (*Ac)[64] = (uint16_t(*)[64])(sh + c * 32768);
        uint16_t (*Bc)[64] = (uint16_t(*)[64])(sh + c * 32768 + 16384);
        uint16_t (*Ao)[64] = (uint16_t(*)[64])(sh + o * 32768);
        uint16_t (*Bo)[64] = (uint16_t(*)[64])(sh + o * 32768 + 16384);
        const int kb1 = (t + 1) * 64;

#pragma unroll
        for (int ks = 0; ks < 2; ++ks) {
            const int swz = ks ? swz1 : swz0;
            bf16x8 a[4], b[4];
#pragma unroll
            for (int mf = 0; mf < 4; ++mf)
                a[mf] = *(const bf16x8*)&Ac[aRowBase + mf * 16][swz];
#pragma unroll
            for (int nf = 0; nf < 4; ++nf)
                b[nf] = *(const bf16x8*)&Bc[bRowBase + nf * 16][swz];
            if (ks == 0 && t < 15) {
#pragma unroll
                for (int cc = 0; cc < 4; ++cc) {
                    GLOAD_LDS16(aBase + (size_t)(cc * 32) * D_ + kb1,
                                &Ao[cc * 32 + w8][0]);
                    GLOAD_LDS16(bBase + (size_t)(cc * 32) * D_ + kb1,
                                &Bo[cc * 32 + w8][0]);
                }
            }
            if (ks == 1 && t < 15) {
                asm volatile("s_waitcnt vmcnt(0)" ::: "memory");
            }
            __builtin_amdgcn_s_barrier();
            __builtin_amdgcn_s_setprio(1);
#pragma unroll
            for (int mf = 0; mf < 4; ++mf)
#pragma unroll
                for (int nf = 0; nf < 4; ++nf)
                    acc[mf][nf] = __builtin_amdgcn_mfma_f32_16x16x32_bf16(
                        a[mf], b[nf], acc[mf][nf], 0, 0, 0);
            if (wn == 0) {   // stats on the 2 wn==0 waves (rows wm*64..+63)
#pragma unroll
                for (int mf = 0; mf < 4; ++mf) {
                    accs[mf] = __builtin_amdgcn_mfma_f32_16x16x32_bf16(
                        a[mf], ones, accs[mf], 0, 0, 0);
                    accq[mf] = __builtin_amdgcn_mfma_f32_16x16x32_bf16(
                        a[mf], a[mf], accq[mf], 0, 0, 0);
                }
            }
            __builtin_amdgcn_s_setprio(0);
        }
    }

    // extract row stats (ssh/qsh live beyond the pipeline region)
    float* qsh = (float*)(sh + 68096);
    if (wn == 0) {
#pragma unroll
        for (int mf = 0; mf < 4; ++mf) {
            if (l16 == 0) {
#pragma unroll
                for (int r = 0; r < 4; ++r)
                    ssh[wm * 64 + mf * 16 + quad * 4 + r] = accs[mf][r];
            }
            if ((l16 >> 2) == quad)
                qsh[wm * 64 + mf * 16 + l16] = accq[mf][l16 & 3];
        }
    }

    __syncthreads();
#pragma unroll
    for (int i = 0; i < 4; ++i)
#pragma unroll
        for (int j = 0; j < 4; ++j)
#pragma unroll
            for (int r = 0; r < 4; ++r)
                epi[wm * 64 + i * 16 + quad * 4 + r][wn * 64 + j * 16 + l16] =
                    acc[i][j][r];
    __syncthreads();

    // epilogue: analytic LN affine, wkv = exp(-exp(tf)*sigmoid(k)) * v
    // row = tid>>1 (128 rows), s-half = (tid&1)*32; wkv also overwrites
    // epi[row][0..63] for the fused part-sum below.
    const int row = tid >> 1, s0 = (tid & 1) * 32;
    const float mu = ssh[row] * (1.f / (float)D_);
    const float var = qsh[row] * (1.f / (float)D_) - mu * mu;
    const float rstd = rsqrtf(var + 1e-5f);
    float* dst = wkv + (size_t)(m0 + row) * S_ + s0;
#pragma unroll
    for (int c4 = 0; c4 < 8; ++c4) {
        float4 kk = *(const float4*)&epi[row][s0 + c4 * 4];
        float4 vv = *(const float4*)&epi[row][64 + s0 + c4 * 4];
        float4 uk4 = *(const float4*)(ucvec + 0 * 64 + s0 + c4 * 4);
        float4 ck4 = *(const float4*)(ucvec + 1 * 64 + s0 + c4 * 4);
        float4 uv4 = *(const float4*)(ucvec + 2 * 64 + s0 + c4 * 4);
        float4 cv4 = *(const float4*)(ucvec + 3 * 64 + s0 + c4 * 4);
        float4 ef = ((const float4*)(efirst + s0))[c4];
        float kx = rstd * (kk.x - mu * uk4.x) + ck4.x;
        float ky = rstd * (kk.y - mu * uk4.y) + ck4.y;
        float kz = rstd * (kk.z - mu * uk4.z) + ck4.z;
        float kw = rstd * (kk.w - mu * uk4.w) + ck4.w;
        float vx = rstd * (vv.x - mu * uv4.x) + cv4.x;
        float vy = rstd * (vv.y - mu * uv4.y) + cv4.y;
        float vz = rstd * (vv.z - mu * uv4.z) + cv4.z;
        float vw = rstd * (vv.w - mu * uv4.w) + cv4.w;
        float4 o;
        o.x = __expf(-ef.x / (1.f + __expf(-kx))) * vx;
        o.y = __expf(-ef.y / (1.f + __expf(-ky))) * vy;
        o.z = __expf(-ef.z / (1.f + __expf(-kz))) * vz;
        o.w = __expf(-ef.w / (1.f + __expf(-kw))) * vw;
        *(float4*)(dst + c4 * 4) = o;
        *(float4*)&epi[row][s0 + c4 * 4] = o;    // stash for part-sum
    }

    // fused k4a: 4 chunks of 32 rows; thread (ch, s) sums its chunk.
    __syncthreads();
    {
        const int ch = tid >> 6, s = tid & 63;
        const float w1 = expf(time_decay[s]);
        float st = 0.f;
#pragma unroll
        for (int t = 0; t < CHKL; ++t)
            st = st * w1 + epi[ch * CHKL + t][s];
        const int b = m0 >> 12;
        const int gc = ((m0 & 4095) >> 5) + ch;
        part[((size_t)b * NCHK + gc) * S_ + s] = st;
    }
}

// ---------------- K4bc: scan with local carry recompute ---------------------
__global__ void k4bc(const float* __restrict__ wkv,
                     const float* __restrict__ time_decay,
                     const float* __restrict__ part,
                     uint16_t* __restrict__ stb,
                     float* __restrict__ last_state)
{
    const int s = threadIdx.x;
    const int bc = blockIdx.x;
    const int b = bc >> 7, c = bc & (NCHK - 1);
    const float td = time_decay[s];
    const float w = expf(td);
    const float wL = expf(td * (float)CHKL);
    const float* pp = part + (size_t)b * NCHK * S_ + s;
    float cin = 0.f;
#pragma unroll 4
    for (int j = 0; j < c; ++j) cin = cin * wL + pp[(size_t)j * S_];
    const float* src = wkv + ((size_t)b * T_ + c * CHKL) * S_ + s;
    uint16_t* dst = stb + ((size_t)b * T_ + c * CHKL) * S_ + s;
    float st = cin;
#pragma unroll
    for (int t = 0; t < CHKL; ++t) {
        st = st * w + src[(size_t)t * S_];
        dst[(size_t)t * S_] = f2bf(st);
    }
    if (c == NCHK - 1) last_state[b * S_ + s] = st;
}

// ---------------- K5: output = states @ Wout^T  (M=32768, N=1024, K=64) ----
__global__ __launch_bounds__(256) void k5_out(
    const uint16_t* __restrict__ st, const uint16_t* __restrict__ Wob,
    float* __restrict__ out)
{
    __shared__ float epi[128][68];   // 34 KB
    const int tid = threadIdx.x;
    const int w = tid >> 6, lane = tid & 63, quad = lane >> 4, l16 = lane & 15;
    const int wm = w >> 1, wn = w & 1;
    const int m0b = blockIdx.y * 128;
    const int n0b = blockIdx.x * 128;

    f32x4 acc[4][4];
#pragma unroll
    for (int i = 0; i < 4; ++i)
#pragma unroll
        for (int j = 0; j < 4; ++j) acc[i][j] = (f32x4){0.f, 0.f, 0.f, 0.f};

#pragma unroll
    for (int k = 0; k < S_; k += 32) {
        bf16x8 a[4], b[4];
#pragma unroll
        for (int i = 0; i < 4; ++i)
            a[i] = *(const bf16x8*)(st + (size_t)(m0b + wm * 64 + i * 16 + l16) * S_ + k + quad * 8);
#pragma unroll
        for (int i = 0; i < 4; ++i)
            b[i] = *(const bf16x8*)(Wob + (size_t)(n0b + wn * 64 + i * 16 + l16) * S_ + k + quad * 8);
#pragma unroll
        for (int i = 0; i < 4; ++i)
#pragma unroll
            for (int j = 0; j < 4; ++j)
                acc[i][j] = __builtin_amdgcn_mfma_f32_16x16x32_bf16(
                    a[i], b[j], acc[i][j], 0, 0, 0);
    }

    const int row = tid >> 1;
    const int c0 = (tid & 1) * 32;
#pragma unroll
    for (int h = 0; h < 2; ++h) {
        __syncthreads();
        if (wn == h) {
#pragma unroll
            for (int i = 0; i < 4; ++i)
#pragma unroll
                for (int j = 0; j < 4; ++j)
#pragma unroll
                    for (int r = 0; r < 4; ++r)
                        epi[wm * 64 + i * 16 + quad * 4 + r][j * 16 + l16] =
                            acc[i][j][r];
        }
        __syncthreads();
        float* dst = out + (size_t)(m0b + row) * D_ + n0b + h * 64 + c0;
#pragma unroll
        for (int c4 = 0; c4 < 8; ++c4)
            ((float4*)dst)[c4] = *(const float4*)&epi[row][c0 + c4 * 4];
    }
}

extern "C" void kernel_launch(void* const* d_in, const int* in_sizes, int n_in,
                              void* d_out, int out_size, void* d_ws, size_t ws_size,
                              hipStream_t stream) {
    const float* x          = (const float*)d_in[0];
    const float* time_decay = (const float*)d_in[1];
    const float* time_first = (const float*)d_in[2];
    const float* W_key      = (const float*)d_in[3];
    const float* W_value    = (const float*)d_in[4];
    const float* W_output   = (const float*)d_in[5];
    const float* W_shift    = (const float*)d_in[6];
    const float* shift_gate = (const float*)d_in[7];
    const float* ln_w       = (const float*)d_in[8];
    const float* ln_b       = (const float*)d_in[9];
    float* out = (float*)d_out;

    char* ws = (char*)d_ws;
    uint16_t* xb      = (uint16_t*)(ws + 0);           // N*D bf16   = 64 MB
    uint16_t* xs      = (uint16_t*)(ws + 67108864);    // N*D bf16   = 64 MB
    float*    wkv     = (float*)   (ws + 134217728);   // N*S f32    =  8 MB
    uint16_t* stb     = (uint16_t*)(ws + 142606336);   // N*S bf16   =  4 MB
    uint16_t* Wsb     = (uint16_t*)(ws + 146800640);   // D*D bf16   =  2 MB
    uint16_t* Wkvb    = (uint16_t*)(ws + 148897792);   // 128*D bf16 = 256 KB
    uint16_t* Wob     = (uint16_t*)(ws + 149159936);   // D*S bf16   = 128 KB
    float*    part    = (float*)   (ws + 149291008);   // B*NCHK*S   = 256 KB
    float*    gbuf    = (float*)   (ws + 149815296);   // D f32      =   4 KB
    float*    efirst  = (float*)   (ws + 149819392);   // S f32      = 256 B
    float*    ucvec   = (float*)   (ws + 149819648);   // 4*S f32    =   1 KB

    prep<<<3554, 256, 0, stream>>>(x, W_shift, W_key, W_value, W_output,
                                   shift_gate, time_first, ln_w, ln_b,
                                   xb, Wsb, Wkvb, Wob, gbuf, efirst, ucvec);
    k1_shift_gemm<<<512, 512, 0, stream>>>(xb, Wsb, gbuf, xs);
    k3_kv<<<256, 256, 0, stream>>>(xs, Wkvb, efirst, ucvec, time_decay,
                                   wkv, part);
    k4bc<<<B_ * NCHK, S_, 0, stream>>>(wkv, time_decay, part, stb,
                                       out + OUT_ELEMS);
    k5_out<<<dim3(8, 256), 256, 0, stream>>>(stb, Wob, out);
}

// Round 9
// 410.842 us; speedup vs baseline: 1.0581x; 1.0395x over previous
//
#include <hip/hip_runtime.h>
#include <stdint.h>

// Problem constants (fixed by setup_inputs)
#define B_ 8
#define T_ 4096
#define D_ 1024
#define S_ 64
#define N_ 32768            // B*T
#define OUT_ELEMS 33554432  // N*D
#define NCHK 128            // scan chunks per batch
#define CHKL 32             // T_/NCHK

typedef __attribute__((ext_vector_type(8))) short bf16x8;
typedef __attribute__((ext_vector_type(8))) unsigned short u16x8;
typedef __attribute__((ext_vector_type(4))) float f32x4;

__device__ __forceinline__ uint16_t f2bf(float f) {
    union { float f; uint32_t u; } v; v.f = f;
    uint32_t r = v.u + 0x7FFFu + ((v.u >> 16) & 1u);
    return (uint16_t)(r >> 16);
}
__device__ __forceinline__ float bf2f(uint16_t h) {
    union { uint32_t u; float f; } v; v.u = ((uint32_t)h) << 16;
    return v.f;
}

// async global->LDS, 16B per lane; LDS dest = wave-uniform base + lane*16
#define GLOAD_LDS16(gp, lp)                                             \
    __builtin_amdgcn_global_load_lds(                                   \
        (const __attribute__((address_space(1))) void*)(gp),            \
        (__attribute__((address_space(3))) void*)(lp), 16, 0, 0)

// ---------------- P0: fused prep --------------------------------------------
__global__ void prep(const float* __restrict__ x,
                     const float* __restrict__ Wsf, const float* __restrict__ Wkf,
                     const float* __restrict__ Wvf, const float* __restrict__ Wof,
                     const float* __restrict__ sg, const float* __restrict__ tf,
                     const float* __restrict__ lnw, const float* __restrict__ lnb,
                     uint16_t* __restrict__ xb, uint16_t* __restrict__ Wsb,
                     uint16_t* __restrict__ Wkvb, uint16_t* __restrict__ Wob,
                     float* __restrict__ gbuf, float* __restrict__ efirst,
                     float* __restrict__ ucvec)
{
    __shared__ float red[4];
    const int blk = blockIdx.x, tid = threadIdx.x;
    if (blk < 2048) {
        for (int i = blk * 256 + tid; i < OUT_ELEMS / 4; i += 2048 * 256) {
            float4 v = ((const float4*)x)[i];
            ushort4 o;
            o.x = f2bf(v.x); o.y = f2bf(v.y); o.z = f2bf(v.z); o.w = f2bf(v.w);
            ((ushort4*)xb)[i] = o;
        }
        return;
    }
    if (blk < 3298) {
        int i = (blk - 2048) * 256 + tid;
        const float* src; uint16_t* dst; int j; bool fold = false;
        if (i < 262144) { src = Wsf; dst = Wsb; j = i; }
        else if (i < 278528) { src = Wkf; dst = Wkvb; j = i - 262144; fold = true; }
        else if (i < 294912) { src = Wvf; dst = Wkvb + 65536; j = i - 278528; fold = true; }
        else if (i < 311296) { src = Wof; dst = Wob; j = i - 294912; }
        else if (i < 311552) {
            j = i - 311296;
            float4 v = ((const float4*)sg)[j];
            float4 g;
            g.x = 1.f / (1.f + __expf(-v.x)); g.y = 1.f / (1.f + __expf(-v.y));
            g.z = 1.f / (1.f + __expf(-v.z)); g.w = 1.f / (1.f + __expf(-v.w));
            ((float4*)gbuf)[j] = g;
            return;
        } else if (i < 311568) {
            j = i - 311552;
            float4 v = ((const float4*)tf)[j];
            float4 e;
            e.x = __expf(v.x); e.y = __expf(v.y); e.z = __expf(v.z); e.w = __expf(v.w);
            ((float4*)efirst)[j] = e;
            return;
        } else return;
        float4 v = ((const float4*)src)[j];
        if (fold) {
            float4 l = ((const float4*)lnw)[j & 255];   // col4 within row of 1024
            v.x *= l.x; v.y *= l.y; v.z *= l.z; v.w *= l.w;
        }
        ushort4 o;
        o.x = f2bf(v.x); o.y = f2bf(v.y); o.z = f2bf(v.z); o.w = f2bf(v.w);
        ((ushort4*)dst)[j] = o;
        return;
    }
    {
        int b2 = blk - 3298;
        int which = b2 >> 6, s = b2 & 63;      // 0:uk 1:ck 2:uv 3:cv
        const float* W = (which < 2) ? Wkf : Wvf;
        const float* L = (which & 1) ? lnb : lnw;
        float4 wv = ((const float4*)W)[s * 256 + tid];
        float4 lv = ((const float4*)L)[tid];
        float p = wv.x * lv.x + wv.y * lv.y + wv.z * lv.z + wv.w * lv.w;
#pragma unroll
        for (int off = 32; off; off >>= 1) p += __shfl_xor(p, off);
        if ((tid & 63) == 0) red[tid >> 6] = p;
        __syncthreads();
        if (tid == 0) ucvec[which * 64 + s] = red[0] + red[1] + red[2] + red[3];
    }
}

// ---------------- K1: x_shift = (x_cat @ Wshift^T)*g + x*(1-g) -> bf16 ------
// 256x256 tile, BK=64, 512 threads = 8 waves (2M x 4N), wave tile 128x64.
// 2 slots x 64KB LDS, distance-1 prefetch, one vmcnt drain per 64 MFMAs.
__global__ __launch_bounds__(512, 2) void k1_shift_gemm(
    const uint16_t* __restrict__ xb, const uint16_t* __restrict__ Wsb,
    const float* __restrict__ gbuf, uint16_t* __restrict__ xs)
{
    __shared__ char sh[131072];                 // 2 slots x (A 32KB + B 32KB)

    const int tid = threadIdx.x;
    const int w = tid >> 6, lane = tid & 63, quad = lane >> 4, l16 = lane & 15;
    const int wm = w >> 2, wn = w & 3;          // 2M x 4N waves
    const int w8 = w * 8;                       // staging row base per wave

    const int lin = blockIdx.x;                 // 512 blocks
    const int idx = lin >> 3;                   // [0,64)
    const int nt = idx & 3;
    const int mt = (lin & 7) * 16 + (idx >> 2); // XCD-local m-ranges
    const int m0 = mt * 256, n0 = nt * 256;
    const int m0x = m0 ^ 2048;                  // x_cat[t] = x[t ^ T/2]; no straddle

    const int arow = w8 + (lane >> 3);
    const int scg  = ((lane & 7) ^ ((lane >> 3) & 7)) * 8;
    const uint16_t* aBase = xb  + (size_t)(m0x + arow) * D_ + scg;
    const uint16_t* bBase = Wsb + (size_t)(n0  + arow) * D_ + scg;

    const int swz0 = ((quad) ^ (l16 & 7)) * 8;        // ks=0
    const int swz1 = ((4 + quad) ^ (l16 & 7)) * 8;    // ks=1
    const int aRowBase = wm * 128 + l16;
    const int bRowBase = wn * 64 + l16;

    f32x4 acc[8][4];
#pragma unroll
    for (int i = 0; i < 8; ++i)
#pragma unroll
        for (int j = 0; j < 4; ++j) acc[i][j] = (f32x4){0.f, 0.f, 0.f, 0.f};

    {
        uint16_t (*A0)[64] = (uint16_t(*)[64])(sh);
        uint16_t (*B0)[64] = (uint16_t(*)[64])(sh + 32768);
#pragma unroll
        for (int c = 0; c < 4; ++c) {
            GLOAD_LDS16(aBase + (size_t)(c * 64) * D_, &A0[c * 64 + w8][0]);
            GLOAD_LDS16(bBase + (size_t)(c * 64) * D_, &B0[c * 64 + w8][0]);
        }
    }
    asm volatile("s_waitcnt vmcnt(0)" ::: "memory");
    __builtin_amdgcn_s_barrier();

#pragma unroll 1
    for (int t = 0; t < 16; ++t) {
        const int c = t & 1, o = c ^ 1;
        uint16_t (*Ac)[64] = (uint16_t(*)[64])(sh + c * 65536);
        uint16_t (*Bc)[64] = (uint16_t(*)[64])(sh + c * 65536 + 32768);
        uint16_t (*Ao)[64] = (uint16_t(*)[64])(sh + o * 65536);
        uint16_t (*Bo)[64] = (uint16_t(*)[64])(sh + o * 65536 + 32768);
        const int kb1 = (t + 1) * 64;

#pragma unroll
        for (int ks = 0; ks < 2; ++ks) {
            const int swz = ks ? swz1 : swz0;
            bf16x8 a[8], b[4];
#pragma unroll
            for (int mf = 0; mf < 8; ++mf)
                a[mf] = *(const bf16x8*)&Ac[aRowBase + mf * 16][swz];
#pragma unroll
            for (int nf = 0; nf < 4; ++nf)
                b[nf] = *(const bf16x8*)&Bc[bRowBase + nf * 16][swz];
            if (ks == 0 && t < 15) {
#pragma unroll
                for (int cc = 0; cc < 4; ++cc) {
                    GLOAD_LDS16(aBase + (size_t)(cc * 64) * D_ + kb1,
                                &Ao[cc * 64 + w8][0]);
                    GLOAD_LDS16(bBase + (size_t)(cc * 64) * D_ + kb1,
                                &Bo[cc * 64 + w8][0]);
                }
            }
            if (ks == 1 && t < 15) {
                asm volatile("s_waitcnt vmcnt(0)" ::: "memory");
            }
            __builtin_amdgcn_s_barrier();
            __builtin_amdgcn_s_setprio(1);
#pragma unroll
            for (int mf = 0; mf < 8; ++mf)
#pragma unroll
                for (int nf = 0; nf < 4; ++nf)
                    acc[mf][nf] = __builtin_amdgcn_mfma_f32_16x16x32_bf16(
                        a[mf], b[nf], acc[mf][nf], 0, 0, 0);
            __builtin_amdgcn_s_setprio(0);
        }
    }

    float (*epi)[260] = (float(*)[260])sh;       // 64 x 260 f32 = 65 KB
    const int row = tid >> 3;
    const int c0 = (tid & 7) * 32;
#pragma unroll
    for (int mb = 0; mb < 4; ++mb) {
        __syncthreads();
        if (wm == (mb >> 1)) {
#pragma unroll
            for (int mf = 0; mf < 4; ++mf)
#pragma unroll
                for (int nf = 0; nf < 4; ++nf)
#pragma unroll
                    for (int r = 0; r < 4; ++r)
                        epi[mf * 16 + quad * 4 + r][wn * 64 + nf * 16 + l16] =
                            acc[(mb & 1) * 4 + mf][nf][r];
        }
        __syncthreads();
        const int grow = m0 + mb * 64 + row;
        const uint16_t* xrow = xb + (size_t)grow * D_ + n0 + c0;
        uint16_t* orow = xs + (size_t)grow * D_ + n0 + c0;
#pragma unroll
        for (int c4 = 0; c4 < 8; ++c4) {
            float4 g4 = ((const float4*)(gbuf + n0 + c0))[c4];
            ushort4 xh = ((const ushort4*)xrow)[c4];
            const float* e = &epi[row][c0 + c4 * 4];
            ushort4 o;
            o.x = f2bf(e[0] * g4.x + bf2f(xh.x) * (1.f - g4.x));
            o.y = f2bf(e[1] * g4.y + bf2f(xh.y) * (1.f - g4.y));
            o.z = f2bf(e[2] * g4.z + bf2f(xh.z) * (1.f - g4.z));
            o.w = f2bf(e[3] * g4.w + bf2f(xh.w) * (1.f - g4.w));
            ((ushort4*)orow)[c4] = o;
        }
    }
}

// ---------------- K3: k/v projection, 64x128 tile, 2-slot pipeline ----------
// grid 512 (3 blocks/CU for TLP) + MFMA row stats + analytic LN + wkv +
// fused k4a part sums. 256 threads = 4 waves (2M x 2N), wave tile 32x64.
__global__ __launch_bounds__(256) void k3_kv(
    const uint16_t* __restrict__ xsb, const uint16_t* __restrict__ Wkvb,
    const float* __restrict__ efirst, const float* __restrict__ ucvec,
    const float* __restrict__ time_decay,
    float* __restrict__ wkv, float* __restrict__ part)
{
    __shared__ char sh[49664];
    // pipeline: 2 slots x (A[64][64] 8KB + B[128][64] 16KB) = 48KB
    float (*epi)[132] = (float(*)[132])sh;       // [64][132] f32 = 33.8KB (union)
    float* ssh = (float*)(sh + 49152);           // [64] row sums
    float* qsh = (float*)(sh + 49408);           // [64] row sumsq

    const int tid = threadIdx.x;
    const int w = tid >> 6, lane = tid & 63, quad = lane >> 4, l16 = lane & 15;
    const int wm = w >> 1, wn = w & 1;
    const int w8 = w * 8;
    const int m0 = blockIdx.x * 64;

    const int arow = w8 + (lane >> 3);           // 0..31 across 4 waves
    const int scg  = ((lane & 7) ^ ((lane >> 3) & 7)) * 8;
    const uint16_t* aBase = xsb + (size_t)(m0 + arow) * D_ + scg;
    const uint16_t* bBase = Wkvb + (size_t)arow * D_ + scg;

    const int swz0 = ((quad) ^ (l16 & 7)) * 8;
    const int swz1 = ((4 + quad) ^ (l16 & 7)) * 8;
    const int aRowBase = wm * 32 + l16;
    const int bRowBase = wn * 64 + l16;

    f32x4 acc[2][4];
#pragma unroll
    for (int i = 0; i < 2; ++i)
#pragma unroll
        for (int j = 0; j < 4; ++j) acc[i][j] = (f32x4){0.f, 0.f, 0.f, 0.f};
    f32x4 accs[2], accq[2];
#pragma unroll
    for (int i = 0; i < 2; ++i) {
        accs[i] = (f32x4){0.f, 0.f, 0.f, 0.f};
        accq[i] = (f32x4){0.f, 0.f, 0.f, 0.f};
    }
    bf16x8 ones;
#pragma unroll
    for (int j = 0; j < 8; ++j) ones[j] = (short)0x3F80;  // bf16 1.0

    // prologue: stage K-tile 0 into slot 0 (A: 2 calls, B: 4 calls)
    {
        uint16_t (*A0)[64] = (uint16_t(*)[64])(sh);
        uint16_t (*B0)[64] = (uint16_t(*)[64])(sh + 8192);
#pragma unroll
        for (int c = 0; c < 2; ++c)
            GLOAD_LDS16(aBase + (size_t)(c * 32) * D_, &A0[c * 32 + w8][0]);
#pragma unroll
        for (int c = 0; c < 4; ++c)
            GLOAD_LDS16(bBase + (size_t)(c * 32) * D_, &B0[c * 32 + w8][0]);
    }
    asm volatile("s_waitcnt vmcnt(0)" ::: "memory");
    __builtin_amdgcn_s_barrier();

#pragma unroll 1
    for (int t = 0; t < 16; ++t) {
        const int c = t & 1, o = c ^ 1;
        uint16_t (*Ac)[64] = (uint16_t(*)[64])(sh + c * 24576);
        uint16_t (*Bc)[64] = (uint16_t(*)[64])(sh + c * 24576 + 8192);
        uint16_t (*Ao)[64] = (uint16_t(*)[64])(sh + o * 24576);
        uint16_t (*Bo)[64] = (uint16_t(*)[64])(sh + o * 24576 + 8192);
        const int kb1 = (t + 1) * 64;

#pragma unroll
        for (int ks = 0; ks < 2; ++ks) {
            const int swz = ks ? swz1 : swz0;
            bf16x8 a[2], b[4];
#pragma unroll
            for (int mf = 0; mf < 2; ++mf)
                a[mf] = *(const bf16x8*)&Ac[aRowBase + mf * 16][swz];
#pragma unroll
            for (int nf = 0; nf < 4; ++nf)
                b[nf] = *(const bf16x8*)&Bc[bRowBase + nf * 16][swz];
            if (ks == 0 && t < 15) {
#pragma unroll
                for (int cc = 0; cc < 2; ++cc)
                    GLOAD_LDS16(aBase + (size_t)(cc * 32) * D_ + kb1,
                                &Ao[cc * 32 + w8][0]);
#pragma unroll
                for (int cc = 0; cc < 4; ++cc)
                    GLOAD_LDS16(bBase + (size_t)(cc * 32) * D_ + kb1,
                                &Bo[cc * 32 + w8][0]);
            }
            if (ks == 1 && t < 15) {
                asm volatile("s_waitcnt vmcnt(0)" ::: "memory");
            }
            __builtin_amdgcn_s_barrier();
            __builtin_amdgcn_s_setprio(1);
#pragma unroll
            for (int mf = 0; mf < 2; ++mf)
#pragma unroll
                for (int nf = 0; nf < 4; ++nf)
                    acc[mf][nf] = __builtin_amdgcn_mfma_f32_16x16x32_bf16(
                        a[mf], b[nf], acc[mf][nf], 0, 0, 0);
            if (wn == 0) {   // stats on the 2 wn==0 waves (rows wm*32..+31)
#pragma unroll
                for (int mf = 0; mf < 2; ++mf) {
                    accs[mf] = __builtin_amdgcn_mfma_f32_16x16x32_bf16(
                        a[mf], ones, accs[mf], 0, 0, 0);
                    accq[mf] = __builtin_amdgcn_mfma_f32_16x16x32_bf16(
                        a[mf], a[mf], accq[mf], 0, 0, 0);
                }
            }
            __builtin_amdgcn_s_setprio(0);
        }
    }

    // extract row stats: C layout col=lane&15, row=quad*4+reg
    if (wn == 0) {
#pragma unroll
        for (int i = 0; i < 2; ++i) {
            if (l16 == 0) {
#pragma unroll
                for (int r = 0; r < 4; ++r)
                    ssh[wm * 32 + i * 16 + quad * 4 + r] = accs[i][r];
            }
            if ((l16 >> 2) == quad)
                qsh[wm * 32 + i * 16 + l16] = accq[i][l16 & 3];
        }
    }

    __syncthreads();
#pragma unroll
    for (int i = 0; i < 2; ++i)
#pragma unroll
        for (int j = 0; j < 4; ++j)
#pragma unroll
            for (int r = 0; r < 4; ++r)
                epi[wm * 32 + i * 16 + quad * 4 + r][wn * 64 + j * 16 + l16] =
                    acc[i][j][r];
    __syncthreads();

    // epilogue: analytic LN affine then wkv = exp(-exp(tf)*sigmoid(k)) * v
    const int row = tid >> 2, s0 = (tid & 3) * 16;
    const float mu = ssh[row] * (1.f / (float)D_);
    const float var = qsh[row] * (1.f / (float)D_) - mu * mu;
    const float rstd = rsqrtf(var + 1e-5f);
    float* dst = wkv + (size_t)(m0 + row) * S_ + s0;
#pragma unroll
    for (int c4 = 0; c4 < 4; ++c4) {
        float4 kk = *(const float4*)&epi[row][s0 + c4 * 4];
        float4 vv = *(const float4*)&epi[row][64 + s0 + c4 * 4];
        float4 uk4 = *(const float4*)(ucvec + 0 * 64 + s0 + c4 * 4);
        float4 ck4 = *(const float4*)(ucvec + 1 * 64 + s0 + c4 * 4);
        float4 uv4 = *(const float4*)(ucvec + 2 * 64 + s0 + c4 * 4);
        float4 cv4 = *(const float4*)(ucvec + 3 * 64 + s0 + c4 * 4);
        float4 ef = ((const float4*)(efirst + s0))[c4];
        float kx = rstd * (kk.x - mu * uk4.x) + ck4.x;
        float ky = rstd * (kk.y - mu * uk4.y) + ck4.y;
        float kz = rstd * (kk.z - mu * uk4.z) + ck4.z;
        float kw = rstd * (kk.w - mu * uk4.w) + ck4.w;
        float vx = rstd * (vv.x - mu * uv4.x) + cv4.x;
        float vy = rstd * (vv.y - mu * uv4.y) + cv4.y;
        float vz = rstd * (vv.z - mu * uv4.z) + cv4.z;
        float vw = rstd * (vv.w - mu * uv4.w) + cv4.w;
        float4 o;
        o.x = __expf(-ef.x / (1.f + __expf(-kx))) * vx;
        o.y = __expf(-ef.y / (1.f + __expf(-ky))) * vy;
        o.z = __expf(-ef.z / (1.f + __expf(-kz))) * vz;
        o.w = __expf(-ef.w / (1.f + __expf(-kw))) * vw;
        *(float4*)(dst + c4 * 4) = o;
        *(float4*)&epi[row][s0 + c4 * 4] = o;    // stash for part-sum
    }

    // fused k4a: 2 chunks of 32 rows; thread (ch, s) on tid<128 sums its chunk.
    __syncthreads();
    if (tid < 128) {
        const int ch = tid >> 6, s = tid & 63;
        const float w1 = expf(time_decay[s]);
        float st = 0.f;
#pragma unroll
        for (int t = 0; t < CHKL; ++t)
            st = st * w1 + epi[ch * CHKL + t][s];
        const int b = m0 >> 12;
        const int gc = ((m0 & 4095) >> 5) + ch;
        part[((size_t)b * NCHK + gc) * S_ + s] = st;
    }
}

// ---------------- K5: fused scan (once per m-block, 2-way n-split) + GEMM ---
// grid dim3(2, 256): blockIdx.y = m-block (128 rows = 4 chunks), blockIdx.x =
// n-half (512 cols). Wave w scans chunk c0+w into swizzled LDS bf16 (R7-
// verified layout), then 4 n-tiles of 128 cols GEMM from LDS. stb eliminated.
__global__ __launch_bounds__(256) void k5_out(
    const float* __restrict__ wkv, const float* __restrict__ part,
    const float* __restrict__ time_decay, const uint16_t* __restrict__ Wob,
    float* __restrict__ out, float* __restrict__ last_state)
{
    __shared__ char sh[51200];
    uint16_t (*stS)[64] = (uint16_t(*)[64])sh;      // [128][64] bf16, 16 KB
    float (*epi)[68] = (float(*)[68])(sh + 16384);  // [128][68] f32, 34.8 KB

    const int tid = threadIdx.x;
    const int w = tid >> 6, lane = tid & 63, quad = lane >> 4, l16 = lane & 15;
    const int wm = w >> 1, wn = w & 1;
    const int m0b = blockIdx.y * 128;
    const int h = blockIdx.x;                       // n-half

    // ---- scan phase: wave w owns chunk c = c0 + w (R7-verified) ------------
    {
        const int b = m0b >> 12;
        const int c = ((m0b & 4095) >> 5) + w;
        const float td = time_decay[lane];
        const float w1 = expf(td);
        const float wL = expf(td * (float)CHKL);
        const float* pp = part + (size_t)b * NCHK * S_ + lane;
        float cin = 0.f;
#pragma unroll 4
        for (int j = 0; j < c; ++j) cin = cin * wL + pp[(size_t)j * S_];
        const float* src = wkv + (size_t)(m0b + w * CHKL) * S_ + lane;
        float st = cin;
#pragma unroll
        for (int t = 0; t < CHKL; ++t) {
            st = st * w1 + src[(size_t)t * S_];
            const int row = w * CHKL + t;
            stS[row][(((lane >> 3) ^ (row & 7)) << 3) | (lane & 7)] = f2bf(st);
        }
        if (h == 0 && c == NCHK - 1)
            last_state[b * S_ + lane] = st;
    }
    __syncthreads();

    // ---- GEMM over 4 n-tiles of 128 cols -----------------------------------
#pragma unroll 1
    for (int nt = 0; nt < 4; ++nt) {
        const int n0b = h * 512 + nt * 128;
        f32x4 acc[4][4];
#pragma unroll
        for (int i = 0; i < 4; ++i)
#pragma unroll
            for (int j = 0; j < 4; ++j) acc[i][j] = (f32x4){0.f, 0.f, 0.f, 0.f};

#pragma unroll
        for (int k = 0; k < S_; k += 32) {
            bf16x8 a[4], b[4];
#pragma unroll
            for (int i = 0; i < 4; ++i) {
                const int row = wm * 64 + i * 16 + l16;
                a[i] = *(const bf16x8*)&stS[row]
                           [((((k >> 3) + quad) ^ (l16 & 7)) * 8)];
            }
#pragma unroll
            for (int i = 0; i < 4; ++i)
                b[i] = *(const bf16x8*)(Wob + (size_t)(n0b + wn * 64 + i * 16 + l16) * S_ + k + quad * 8);
#pragma unroll
            for (int i = 0; i < 4; ++i)
#pragma unroll
                for (int j = 0; j < 4; ++j)
                    acc[i][j] = __builtin_amdgcn_mfma_f32_16x16x32_bf16(
                        a[i], b[j], acc[i][j], 0, 0, 0);
        }

        const int row = tid >> 1;
        const int c0 = (tid & 1) * 32;
#pragma unroll
        for (int hh = 0; hh < 2; ++hh) {
            __syncthreads();
            if (wn == hh) {
#pragma unroll
                for (int i = 0; i < 4; ++i)
#pragma unroll
                    for (int j = 0; j < 4; ++j)
#pragma unroll
                        for (int r = 0; r < 4; ++r)
                            epi[wm * 64 + i * 16 + quad * 4 + r][j * 16 + l16] =
                                acc[i][j][r];
            }
            __syncthreads();
            float* dst = out + (size_t)(m0b + row) * D_ + n0b + hh * 64 + c0;
#pragma unroll
            for (int c4 = 0; c4 < 8; ++c4)
                ((float4*)dst)[c4] = *(const float4*)&epi[row][c0 + c4 * 4];
        }
    }
}

extern "C" void kernel_launch(void* const* d_in, const int* in_sizes, int n_in,
                              void* d_out, int out_size, void* d_ws, size_t ws_size,
                              hipStream_t stream) {
    const float* x          = (const float*)d_in[0];
    const float* time_decay = (const float*)d_in[1];
    const float* time_first = (const float*)d_in[2];
    const float* W_key      = (const float*)d_in[3];
    const float* W_value    = (const float*)d_in[4];
    const float* W_output   = (const float*)d_in[5];
    const float* W_shift    = (const float*)d_in[6];
    const float* shift_gate = (const float*)d_in[7];
    const float* ln_w       = (const float*)d_in[8];
    const float* ln_b       = (const float*)d_in[9];
    float* out = (float*)d_out;

    char* ws = (char*)d_ws;
    uint16_t* xb      = (uint16_t*)(ws + 0);           // N*D bf16   = 64 MB
    uint16_t* xs      = (uint16_t*)(ws + 67108864);    // N*D bf16   = 64 MB
    float*    wkv     = (float*)   (ws + 134217728);   // N*S f32    =  8 MB
    uint16_t* Wsb     = (uint16_t*)(ws + 146800640);   // D*D bf16   =  2 MB
    uint16_t* Wkvb    = (uint16_t*)(ws + 148897792);   // 128*D bf16 = 256 KB
    uint16_t* Wob     = (uint16_t*)(ws + 149159936);   // D*S bf16   = 128 KB
    float*    part    = (float*)   (ws + 149291008);   // B*NCHK*S   = 256 KB
    float*    gbuf    = (float*)   (ws + 149815296);   // D f32      =   4 KB
    float*    efirst  = (float*)   (ws + 149819392);   // S f32      = 256 B
    float*    ucvec   = (float*)   (ws + 149819648);   // 4*S f32    =   1 KB

    prep<<<3554, 256, 0, stream>>>(x, W_shift, W_key, W_value, W_output,
                                   shift_gate, time_first, ln_w, ln_b,
                                   xb, Wsb, Wkvb, Wob, gbuf, efirst, ucvec);
    k1_shift_gemm<<<512, 512, 0, stream>>>(xb, Wsb, gbuf, xs);
    k3_kv<<<512, 256, 0, stream>>>(xs, Wkvb, efirst, ucvec, time_decay,
                                   wkv, part);
    k5_out<<<dim3(2, 256), 256, 0, stream>>>(wkv, part, time_decay, Wob,
                                             out, out + OUT_ELEMS);
}

// Round 10
// 379.151 us; speedup vs baseline: 1.1466x; 1.0836x over previous
//
#include <hip/hip_runtime.h>
#include <stdint.h>

// Problem constants (fixed by setup_inputs)
#define B_ 8
#define T_ 4096
#define D_ 1024
#define S_ 64
#define N_ 32768            // B*T
#define OUT_ELEMS 33554432  // N*D
#define NCHK 128            // scan chunks per batch
#define CHKL 32             // T_/NCHK

typedef __attribute__((ext_vector_type(8))) short bf16x8;
typedef __attribute__((ext_vector_type(8))) unsigned short u16x8;
typedef __attribute__((ext_vector_type(4))) float f32x4;

__device__ __forceinline__ uint16_t f2bf(float f) {
    union { float f; uint32_t u; } v; v.f = f;
    uint32_t r = v.u + 0x7FFFu + ((v.u >> 16) & 1u);
    return (uint16_t)(r >> 16);
}
__device__ __forceinline__ float bf2f(uint16_t h) {
    union { uint32_t u; float f; } v; v.u = ((uint32_t)h) << 16;
    return v.f;
}

// async global->LDS, 16B per lane; LDS dest = wave-uniform base + lane*16
#define GLOAD_LDS16(gp, lp)                                             \
    __builtin_amdgcn_global_load_lds(                                   \
        (const __attribute__((address_space(1))) void*)(gp),            \
        (__attribute__((address_space(3))) void*)(lp), 16, 0, 0)

// ---------------- P0: fused prep --------------------------------------------
__global__ void prep(const float* __restrict__ x,
                     const float* __restrict__ Wsf, const float* __restrict__ Wkf,
                     const float* __restrict__ Wvf, const float* __restrict__ Wof,
                     const float* __restrict__ sg, const float* __restrict__ tf,
                     const float* __restrict__ lnw, const float* __restrict__ lnb,
                     uint16_t* __restrict__ xb, uint16_t* __restrict__ Wsb,
                     uint16_t* __restrict__ Wkvb, uint16_t* __restrict__ Wob,
                     float* __restrict__ gbuf, float* __restrict__ efirst,
                     float* __restrict__ ucvec)
{
    __shared__ float red[4];
    const int blk = blockIdx.x, tid = threadIdx.x;
    if (blk < 2048) {
        for (int i = blk * 256 + tid; i < OUT_ELEMS / 4; i += 2048 * 256) {
            float4 v = ((const float4*)x)[i];
            ushort4 o;
            o.x = f2bf(v.x); o.y = f2bf(v.y); o.z = f2bf(v.z); o.w = f2bf(v.w);
            ((ushort4*)xb)[i] = o;
        }
        return;
    }
    if (blk < 3298) {
        int i = (blk - 2048) * 256 + tid;
        const float* src; uint16_t* dst; int j; bool fold = false;
        if (i < 262144) { src = Wsf; dst = Wsb; j = i; }
        else if (i < 278528) { src = Wkf; dst = Wkvb; j = i - 262144; fold = true; }
        else if (i < 294912) { src = Wvf; dst = Wkvb + 65536; j = i - 278528; fold = true; }
        else if (i < 311296) { src = Wof; dst = Wob; j = i - 294912; }
        else if (i < 311552) {
            j = i - 311296;
            float4 v = ((const float4*)sg)[j];
            float4 g;
            g.x = 1.f / (1.f + __expf(-v.x)); g.y = 1.f / (1.f + __expf(-v.y));
            g.z = 1.f / (1.f + __expf(-v.z)); g.w = 1.f / (1.f + __expf(-v.w));
            ((float4*)gbuf)[j] = g;
            return;
        } else if (i < 311568) {
            j = i - 311552;
            float4 v = ((const float4*)tf)[j];
            float4 e;
            e.x = __expf(v.x); e.y = __expf(v.y); e.z = __expf(v.z); e.w = __expf(v.w);
            ((float4*)efirst)[j] = e;
            return;
        } else return;
        float4 v = ((const float4*)src)[j];
        if (fold) {
            float4 l = ((const float4*)lnw)[j & 255];   // col4 within row of 1024
            v.x *= l.x; v.y *= l.y; v.z *= l.z; v.w *= l.w;
        }
        ushort4 o;
        o.x = f2bf(v.x); o.y = f2bf(v.y); o.z = f2bf(v.z); o.w = f2bf(v.w);
        ((ushort4*)dst)[j] = o;
        return;
    }
    {
        int b2 = blk - 3298;
        int which = b2 >> 6, s = b2 & 63;      // 0:uk 1:ck 2:uv 3:cv
        const float* W = (which < 2) ? Wkf : Wvf;
        const float* L = (which & 1) ? lnb : lnw;
        float4 wv = ((const float4*)W)[s * 256 + tid];
        float4 lv = ((const float4*)L)[tid];
        float p = wv.x * lv.x + wv.y * lv.y + wv.z * lv.z + wv.w * lv.w;
#pragma unroll
        for (int off = 32; off; off >>= 1) p += __shfl_xor(p, off);
        if ((tid & 63) == 0) red[tid >> 6] = p;
        __syncthreads();
        if (tid == 0) ucvec[which * 64 + s] = red[0] + red[1] + red[2] + red[3];
    }
}

// ---------------- K1: x_shift = (x_cat @ Wshift^T)*g + x*(1-g) -> bf16 ------
// 256x256 tile, BK=64, 512 threads = 8 waves (2M x 4N), wave tile 128x64.
// 2 slots x 64KB LDS, distance-1 prefetch, one vmcnt drain per 64 MFMAs.
__global__ __launch_bounds__(512, 2) void k1_shift_gemm(
    const uint16_t* __restrict__ xb, const uint16_t* __restrict__ Wsb,
    const float* __restrict__ gbuf, uint16_t* __restrict__ xs)
{
    __shared__ char sh[131072];                 // 2 slots x (A 32KB + B 32KB)

    const int tid = threadIdx.x;
    const int w = tid >> 6, lane = tid & 63, quad = lane >> 4, l16 = lane & 15;
    const int wm = w >> 2, wn = w & 3;          // 2M x 4N waves
    const int w8 = w * 8;                       // staging row base per wave

    const int lin = blockIdx.x;                 // 512 blocks
    const int idx = lin >> 3;                   // [0,64)
    const int nt = idx & 3;
    const int mt = (lin & 7) * 16 + (idx >> 2); // XCD-local m-ranges
    const int m0 = mt * 256, n0 = nt * 256;
    const int m0x = m0 ^ 2048;                  // x_cat[t] = x[t ^ T/2]; no straddle

    const int arow = w8 + (lane >> 3);
    const int scg  = ((lane & 7) ^ ((lane >> 3) & 7)) * 8;
    const uint16_t* aBase = xb  + (size_t)(m0x + arow) * D_ + scg;
    const uint16_t* bBase = Wsb + (size_t)(n0  + arow) * D_ + scg;

    const int swz0 = ((quad) ^ (l16 & 7)) * 8;        // ks=0
    const int swz1 = ((4 + quad) ^ (l16 & 7)) * 8;    // ks=1
    const int aRowBase = wm * 128 + l16;
    const int bRowBase = wn * 64 + l16;

    f32x4 acc[8][4];
#pragma unroll
    for (int i = 0; i < 8; ++i)
#pragma unroll
        for (int j = 0; j < 4; ++j) acc[i][j] = (f32x4){0.f, 0.f, 0.f, 0.f};

    {
        uint16_t (*A0)[64] = (uint16_t(*)[64])(sh);
        uint16_t (*B0)[64] = (uint16_t(*)[64])(sh + 32768);
#pragma unroll
        for (int c = 0; c < 4; ++c) {
            GLOAD_LDS16(aBase + (size_t)(c * 64) * D_, &A0[c * 64 + w8][0]);
            GLOAD_LDS16(bBase + (size_t)(c * 64) * D_, &B0[c * 64 + w8][0]);
        }
    }
    asm volatile("s_waitcnt vmcnt(0)" ::: "memory");
    __builtin_amdgcn_s_barrier();

#pragma unroll 1
    for (int t = 0; t < 16; ++t) {
        const int c = t & 1, o = c ^ 1;
        uint16_t (*Ac)[64] = (uint16_t(*)[64])(sh + c * 65536);
        uint16_t (*Bc)[64] = (uint16_t(*)[64])(sh + c * 65536 + 32768);
        uint16_t (*Ao)[64] = (uint16_t(*)[64])(sh + o * 65536);
        uint16_t (*Bo)[64] = (uint16_t(*)[64])(sh + o * 65536 + 32768);
        const int kb1 = (t + 1) * 64;

#pragma unroll
        for (int ks = 0; ks < 2; ++ks) {
            const int swz = ks ? swz1 : swz0;
            bf16x8 a[8], b[4];
#pragma unroll
            for (int mf = 0; mf < 8; ++mf)
                a[mf] = *(const bf16x8*)&Ac[aRowBase + mf * 16][swz];
#pragma unroll
            for (int nf = 0; nf < 4; ++nf)
                b[nf] = *(const bf16x8*)&Bc[bRowBase + nf * 16][swz];
            if (ks == 0 && t < 15) {
#pragma unroll
                for (int cc = 0; cc < 4; ++cc) {
                    GLOAD_LDS16(aBase + (size_t)(cc * 64) * D_ + kb1,
                                &Ao[cc * 64 + w8][0]);
                    GLOAD_LDS16(bBase + (size_t)(cc * 64) * D_ + kb1,
                                &Bo[cc * 64 + w8][0]);
                }
            }
            if (ks == 1 && t < 15) {
                asm volatile("s_waitcnt vmcnt(0)" ::: "memory");
            }
            __builtin_amdgcn_s_barrier();
            __builtin_amdgcn_s_setprio(1);
#pragma unroll
            for (int mf = 0; mf < 8; ++mf)
#pragma unroll
                for (int nf = 0; nf < 4; ++nf)
                    acc[mf][nf] = __builtin_amdgcn_mfma_f32_16x16x32_bf16(
                        a[mf], b[nf], acc[mf][nf], 0, 0, 0);
            __builtin_amdgcn_s_setprio(0);
        }
    }

    float (*epi)[260] = (float(*)[260])sh;       // 64 x 260 f32 = 65 KB
    const int row = tid >> 3;
    const int c0 = (tid & 7) * 32;
#pragma unroll
    for (int mb = 0; mb < 4; ++mb) {
        __syncthreads();
        if (wm == (mb >> 1)) {
#pragma unroll
            for (int mf = 0; mf < 4; ++mf)
#pragma unroll
                for (int nf = 0; nf < 4; ++nf)
#pragma unroll
                    for (int r = 0; r < 4; ++r)
                        epi[mf * 16 + quad * 4 + r][wn * 64 + nf * 16 + l16] =
                            acc[(mb & 1) * 4 + mf][nf][r];
        }
        __syncthreads();
        const int grow = m0 + mb * 64 + row;
        const uint16_t* xrow = xb + (size_t)grow * D_ + n0 + c0;
        uint16_t* orow = xs + (size_t)grow * D_ + n0 + c0;
#pragma unroll
        for (int c4 = 0; c4 < 8; ++c4) {
            float4 g4 = ((const float4*)(gbuf + n0 + c0))[c4];
            ushort4 xh = ((const ushort4*)xrow)[c4];
            const float* e = &epi[row][c0 + c4 * 4];
            ushort4 o;
            o.x = f2bf(e[0] * g4.x + bf2f(xh.x) * (1.f - g4.x));
            o.y = f2bf(e[1] * g4.y + bf2f(xh.y) * (1.f - g4.y));
            o.z = f2bf(e[2] * g4.z + bf2f(xh.z) * (1.f - g4.z));
            o.w = f2bf(e[3] * g4.w + bf2f(xh.w) * (1.f - g4.w));
            ((ushort4*)orow)[c4] = o;
        }
    }
}

// ---------------- K3: k/v projection, 64x128 tile, 2-slot pipeline ----------
// grid 512 (3 blocks/CU for TLP) + MFMA row stats + analytic LN + wkv +
// fused k4a part sums. 256 threads = 4 waves (2M x 2N), wave tile 32x64.
__global__ __launch_bounds__(256) void k3_kv(
    const uint16_t* __restrict__ xsb, const uint16_t* __restrict__ Wkvb,
    const float* __restrict__ efirst, const float* __restrict__ ucvec,
    const float* __restrict__ time_decay,
    float* __restrict__ wkv, float* __restrict__ part)
{
    __shared__ char sh[49664];
    // pipeline: 2 slots x (A[64][64] 8KB + B[128][64] 16KB) = 48KB
    float (*epi)[132] = (float(*)[132])sh;       // [64][132] f32 = 33.8KB (union)
    float* ssh = (float*)(sh + 49152);           // [64] row sums
    float* qsh = (float*)(sh + 49408);           // [64] row sumsq

    const int tid = threadIdx.x;
    const int w = tid >> 6, lane = tid & 63, quad = lane >> 4, l16 = lane & 15;
    const int wm = w >> 1, wn = w & 1;
    const int w8 = w * 8;
    const int m0 = blockIdx.x * 64;

    const int arow = w8 + (lane >> 3);           // 0..31 across 4 waves
    const int scg  = ((lane & 7) ^ ((lane >> 3) & 7)) * 8;
    const uint16_t* aBase = xsb + (size_t)(m0 + arow) * D_ + scg;
    const uint16_t* bBase = Wkvb + (size_t)arow * D_ + scg;

    const int swz0 = ((quad) ^ (l16 & 7)) * 8;
    const int swz1 = ((4 + quad) ^ (l16 & 7)) * 8;
    const int aRowBase = wm * 32 + l16;
    const int bRowBase = wn * 64 + l16;

    f32x4 acc[2][4];
#pragma unroll
    for (int i = 0; i < 2; ++i)
#pragma unroll
        for (int j = 0; j < 4; ++j) acc[i][j] = (f32x4){0.f, 0.f, 0.f, 0.f};
    f32x4 accs[2], accq[2];
#pragma unroll
    for (int i = 0; i < 2; ++i) {
        accs[i] = (f32x4){0.f, 0.f, 0.f, 0.f};
        accq[i] = (f32x4){0.f, 0.f, 0.f, 0.f};
    }
    bf16x8 ones;
#pragma unroll
    for (int j = 0; j < 8; ++j) ones[j] = (short)0x3F80;  // bf16 1.0

    // prologue: stage K-tile 0 into slot 0 (A: 2 calls, B: 4 calls)
    {
        uint16_t (*A0)[64] = (uint16_t(*)[64])(sh);
        uint16_t (*B0)[64] = (uint16_t(*)[64])(sh + 8192);
#pragma unroll
        for (int c = 0; c < 2; ++c)
            GLOAD_LDS16(aBase + (size_t)(c * 32) * D_, &A0[c * 32 + w8][0]);
#pragma unroll
        for (int c = 0; c < 4; ++c)
            GLOAD_LDS16(bBase + (size_t)(c * 32) * D_, &B0[c * 32 + w8][0]);
    }
    asm volatile("s_waitcnt vmcnt(0)" ::: "memory");
    __builtin_amdgcn_s_barrier();

#pragma unroll 1
    for (int t = 0; t < 16; ++t) {
        const int c = t & 1, o = c ^ 1;
        uint16_t (*Ac)[64] = (uint16_t(*)[64])(sh + c * 24576);
        uint16_t (*Bc)[64] = (uint16_t(*)[64])(sh + c * 24576 + 8192);
        uint16_t (*Ao)[64] = (uint16_t(*)[64])(sh + o * 24576);
        uint16_t (*Bo)[64] = (uint16_t(*)[64])(sh + o * 24576 + 8192);
        const int kb1 = (t + 1) * 64;

#pragma unroll
        for (int ks = 0; ks < 2; ++ks) {
            const int swz = ks ? swz1 : swz0;
            bf16x8 a[2], b[4];
#pragma unroll
            for (int mf = 0; mf < 2; ++mf)
                a[mf] = *(const bf16x8*)&Ac[aRowBase + mf * 16][swz];
#pragma unroll
            for (int nf = 0; nf < 4; ++nf)
                b[nf] = *(const bf16x8*)&Bc[bRowBase + nf * 16][swz];
            if (ks == 0 && t < 15) {
#pragma unroll
                for (int cc = 0; cc < 2; ++cc)
                    GLOAD_LDS16(aBase + (size_t)(cc * 32) * D_ + kb1,
                                &Ao[cc * 32 + w8][0]);
#pragma unroll
                for (int cc = 0; cc < 4; ++cc)
                    GLOAD_LDS16(bBase + (size_t)(cc * 32) * D_ + kb1,
                                &Bo[cc * 32 + w8][0]);
            }
            if (ks == 1 && t < 15) {
                asm volatile("s_waitcnt vmcnt(0)" ::: "memory");
            }
            __builtin_amdgcn_s_barrier();
            __builtin_amdgcn_s_setprio(1);
#pragma unroll
            for (int mf = 0; mf < 2; ++mf)
#pragma unroll
                for (int nf = 0; nf < 4; ++nf)
                    acc[mf][nf] = __builtin_amdgcn_mfma_f32_16x16x32_bf16(
                        a[mf], b[nf], acc[mf][nf], 0, 0, 0);
            if (wn == 0) {   // stats on the 2 wn==0 waves (rows wm*32..+31)
#pragma unroll
                for (int mf = 0; mf < 2; ++mf) {
                    accs[mf] = __builtin_amdgcn_mfma_f32_16x16x32_bf16(
                        a[mf], ones, accs[mf], 0, 0, 0);
                    accq[mf] = __builtin_amdgcn_mfma_f32_16x16x32_bf16(
                        a[mf], a[mf], accq[mf], 0, 0, 0);
                }
            }
            __builtin_amdgcn_s_setprio(0);
        }
    }

    // extract row stats: C layout col=lane&15, row=quad*4+reg
    if (wn == 0) {
#pragma unroll
        for (int i = 0; i < 2; ++i) {
            if (l16 == 0) {
#pragma unroll
                for (int r = 0; r < 4; ++r)
                    ssh[wm * 32 + i * 16 + quad * 4 + r] = accs[i][r];
            }
            if ((l16 >> 2) == quad)
                qsh[wm * 32 + i * 16 + l16] = accq[i][l16 & 3];
        }
    }

    __syncthreads();
#pragma unroll
    for (int i = 0; i < 2; ++i)
#pragma unroll
        for (int j = 0; j < 4; ++j)
#pragma unroll
            for (int r = 0; r < 4; ++r)
                epi[wm * 32 + i * 16 + quad * 4 + r][wn * 64 + j * 16 + l16] =
                    acc[i][j][r];
    __syncthreads();

    // epilogue: analytic LN affine then wkv = exp(-exp(tf)*sigmoid(k)) * v
    const int row = tid >> 2, s0 = (tid & 3) * 16;
    const float mu = ssh[row] * (1.f / (float)D_);
    const float var = qsh[row] * (1.f / (float)D_) - mu * mu;
    const float rstd = rsqrtf(var + 1e-5f);
    float* dst = wkv + (size_t)(m0 + row) * S_ + s0;
#pragma unroll
    for (int c4 = 0; c4 < 4; ++c4) {
        float4 kk = *(const float4*)&epi[row][s0 + c4 * 4];
        float4 vv = *(const float4*)&epi[row][64 + s0 + c4 * 4];
        float4 uk4 = *(const float4*)(ucvec + 0 * 64 + s0 + c4 * 4);
        float4 ck4 = *(const float4*)(ucvec + 1 * 64 + s0 + c4 * 4);
        float4 uv4 = *(const float4*)(ucvec + 2 * 64 + s0 + c4 * 4);
        float4 cv4 = *(const float4*)(ucvec + 3 * 64 + s0 + c4 * 4);
        float4 ef = ((const float4*)(efirst + s0))[c4];
        float kx = rstd * (kk.x - mu * uk4.x) + ck4.x;
        float ky = rstd * (kk.y - mu * uk4.y) + ck4.y;
        float kz = rstd * (kk.z - mu * uk4.z) + ck4.z;
        float kw = rstd * (kk.w - mu * uk4.w) + ck4.w;
        float vx = rstd * (vv.x - mu * uv4.x) + cv4.x;
        float vy = rstd * (vv.y - mu * uv4.y) + cv4.y;
        float vz = rstd * (vv.z - mu * uv4.z) + cv4.z;
        float vw = rstd * (vv.w - mu * uv4.w) + cv4.w;
        float4 o;
        o.x = __expf(-ef.x / (1.f + __expf(-kx))) * vx;
        o.y = __expf(-ef.y / (1.f + __expf(-ky))) * vy;
        o.z = __expf(-ef.z / (1.f + __expf(-kz))) * vz;
        o.w = __expf(-ef.w / (1.f + __expf(-kw))) * vw;
        *(float4*)(dst + c4 * 4) = o;
        *(float4*)&epi[row][s0 + c4 * 4] = o;    // stash for part-sum
    }

    // fused k4a: 2 chunks of 32 rows; thread (ch, s) on tid<128 sums its chunk.
    __syncthreads();
    if (tid < 128) {
        const int ch = tid >> 6, s = tid & 63;
        const float w1 = expf(time_decay[s]);
        float st = 0.f;
#pragma unroll
        for (int t = 0; t < CHKL; ++t)
            st = st * w1 + epi[ch * CHKL + t][s];
        const int b = m0 >> 12;
        const int gc = ((m0 & 4095) >> 5) + ch;
        part[((size_t)b * NCHK + gc) * S_ + s] = st;
    }
}

// ---------------- K5: fused scan + output GEMM, 512 threads (16 waves/CU) ---
// grid dim3(2, 256): blockIdx.y = m-block (128 rows = 4 chunks), blockIdx.x =
// n-half (512 cols). Waves 0-3 scan chunks into swizzled LDS bf16 (verified
// layout); all 8 waves (2M x 4N, wave tile 64x32) GEMM 4 n-tiles of 128.
__global__ __launch_bounds__(512) void k5_out(
    const float* __restrict__ wkv, const float* __restrict__ part,
    const float* __restrict__ time_decay, const uint16_t* __restrict__ Wob,
    float* __restrict__ out, float* __restrict__ last_state)
{
    __shared__ char sh[50176];
    uint16_t (*stS)[64] = (uint16_t(*)[64])sh;        // [128][64] bf16, 16 KB
    float (*epi)[132] = (float(*)[132])(sh + 16384);  // [64][132] f32, 33.8 KB

    const int tid = threadIdx.x;
    const int w = tid >> 6, lane = tid & 63, quad = lane >> 4, l16 = lane & 15;
    const int wm = w >> 2, wn = w & 3;                // 2M x 4N
    const int m0b = blockIdx.y * 128;
    const int h = blockIdx.x;                         // n-half

    // ---- scan phase: waves 0-3, wave w owns chunk c0 + w (verified R9) -----
    if (w < 4) {
        const int b = m0b >> 12;
        const int c = ((m0b & 4095) >> 5) + w;
        const float td = time_decay[lane];
        const float w1 = expf(td);
        const float wL = expf(td * (float)CHKL);
        const float* pp = part + (size_t)b * NCHK * S_ + lane;
        float cin = 0.f;
#pragma unroll 4
        for (int j = 0; j < c; ++j) cin = cin * wL + pp[(size_t)j * S_];
        const float* src = wkv + (size_t)(m0b + w * CHKL) * S_ + lane;
        float st = cin;
#pragma unroll
        for (int t = 0; t < CHKL; ++t) {
            st = st * w1 + src[(size_t)t * S_];
            const int row = w * CHKL + t;
            stS[row][(((lane >> 3) ^ (row & 7)) << 3) | (lane & 7)] = f2bf(st);
        }
        if (h == 0 && c == NCHK - 1)
            last_state[b * S_ + lane] = st;
    }
    __syncthreads();

    // ---- GEMM over 4 n-tiles of 128 cols -----------------------------------
#pragma unroll 1
    for (int nt = 0; nt < 4; ++nt) {
        const int n0b = h * 512 + nt * 128;
        f32x4 acc[4][2];
#pragma unroll
        for (int i = 0; i < 4; ++i)
#pragma unroll
            for (int j = 0; j < 2; ++j) acc[i][j] = (f32x4){0.f, 0.f, 0.f, 0.f};

#pragma unroll
        for (int k = 0; k < S_; k += 32) {
            bf16x8 a[4], b[2];
#pragma unroll
            for (int i = 0; i < 4; ++i) {
                const int row = wm * 64 + i * 16 + l16;
                a[i] = *(const bf16x8*)&stS[row]
                           [((((k >> 3) + quad) ^ (l16 & 7)) * 8)];
            }
#pragma unroll
            for (int j = 0; j < 2; ++j)
                b[j] = *(const bf16x8*)(Wob + (size_t)(n0b + wn * 32 + j * 16 + l16) * S_ + k + quad * 8);
#pragma unroll
            for (int i = 0; i < 4; ++i)
#pragma unroll
                for (int j = 0; j < 2; ++j)
                    acc[i][j] = __builtin_amdgcn_mfma_f32_16x16x32_bf16(
                        a[i], b[j], acc[i][j], 0, 0, 0);
        }

        const int srow = tid >> 3;            // 0..63
        const int scol = (tid & 7) * 4;       // interleaved: contiguous per 8 thr
#pragma unroll
        for (int mb = 0; mb < 2; ++mb) {
            __syncthreads();
            if (wm == mb) {
#pragma unroll
                for (int i = 0; i < 4; ++i)
#pragma unroll
                    for (int j = 0; j < 2; ++j)
#pragma unroll
                        for (int r = 0; r < 4; ++r)
                            epi[i * 16 + quad * 4 + r][wn * 32 + j * 16 + l16] =
                                acc[i][j][r];
            }
            __syncthreads();
            float* dst = out + (size_t)(m0b + mb * 64 + srow) * D_ + n0b;
#pragma unroll
            for (int c4 = 0; c4 < 4; ++c4)
                *(float4*)(dst + scol + c4 * 32) =
                    *(const float4*)&epi[srow][scol + c4 * 32];
        }
    }
}

extern "C" void kernel_launch(void* const* d_in, const int* in_sizes, int n_in,
                              void* d_out, int out_size, void* d_ws, size_t ws_size,
                              hipStream_t stream) {
    const float* x          = (const float*)d_in[0];
    const float* time_decay = (const float*)d_in[1];
    const float* time_first = (const float*)d_in[2];
    const float* W_key      = (const float*)d_in[3];
    const float* W_value    = (const float*)d_in[4];
    const float* W_output   = (const float*)d_in[5];
    const float* W_shift    = (const float*)d_in[6];
    const float* shift_gate = (const float*)d_in[7];
    const float* ln_w       = (const float*)d_in[8];
    const float* ln_b       = (const float*)d_in[9];
    float* out = (float*)d_out;

    char* ws = (char*)d_ws;
    uint16_t* xb      = (uint16_t*)(ws + 0);           // N*D bf16   = 64 MB
    uint16_t* xs      = (uint16_t*)(ws + 67108864);    // N*D bf16   = 64 MB
    float*    wkv     = (float*)   (ws + 134217728);   // N*S f32    =  8 MB
    uint16_t* Wsb     = (uint16_t*)(ws + 146800640);   // D*D bf16   =  2 MB
    uint16_t* Wkvb    = (uint16_t*)(ws + 148897792);   // 128*D bf16 = 256 KB
    uint16_t* Wob     = (uint16_t*)(ws + 149159936);   // D*S bf16   = 128 KB
    float*    part    = (float*)   (ws + 149291008);   // B*NCHK*S   = 256 KB
    float*    gbuf    = (float*)   (ws + 149815296);   // D f32      =   4 KB
    float*    efirst  = (float*)   (ws + 149819392);   // S f32      = 256 B
    float*    ucvec   = (float*)   (ws + 149819648);   // 4*S f32    =   1 KB

    prep<<<3554, 256, 0, stream>>>(x, W_shift, W_key, W_value, W_output,
                                   shift_gate, time_first, ln_w, ln_b,
                                   xb, Wsb, Wkvb, Wob, gbuf, efirst, ucvec);
    k1_shift_gemm<<<512, 512, 0, stream>>>(xb, Wsb, gbuf, xs);
    k3_kv<<<512, 256, 0, stream>>>(xs, Wkvb, efirst, ucvec, time_decay,
                                   wkv, part);
    k5_out<<<dim3(2, 256), 512, 0, stream>>>(wkv, part, time_decay, Wob,
                                             out, out + OUT_ELEMS);
}